// Round 15
// baseline (177.341 us; speedup 1.0000x reference)
//
#include <hip/hip_runtime.h>

#define N 8192
#define D 512

typedef __attribute__((ext_vector_type(8))) short short8;
typedef __attribute__((ext_vector_type(4))) float f32x4;

typedef const __attribute__((address_space(1))) unsigned int* gas_t;
typedef __attribute__((address_space(3))) unsigned int* las_t;

static __device__ __forceinline__ unsigned short f2bf(float f) {
    unsigned u = __float_as_uint(f);
    unsigned r = (u + 0x7FFFu + ((u >> 16) & 1u)) >> 16;
    return (unsigned short)r;
}
static __device__ __forceinline__ float bf2f(unsigned u) {
    return __uint_as_float(u << 16);
}
static __device__ __forceinline__ void gl_lds16(const unsigned short* g, char* l) {
    __builtin_amdgcn_global_load_lds((gas_t)g, (las_t)l, 16, 0, 0);
}
// triangle cumulative for the 64x64 grid of 128-wide tiles: row r owns (64-r) tiles
static __device__ __forceinline__ int tri_cum(int r) { return r * (129 - r) / 2; }

// K0: pack thetas -> float4 (x,y,z,|t|^2); init per-row accumulators + d2max + loss acc.
__global__ void kpack(const float* __restrict__ th, float4* __restrict__ th4,
                      float* __restrict__ srow, unsigned* __restrict__ jminrow,
                      unsigned* __restrict__ negrow, unsigned* __restrict__ d2mb,
                      float* __restrict__ gacc) {
    int i = blockIdx.x * 256 + threadIdx.x;
    if (i < N) {
        float x = th[3 * i], y = th[3 * i + 1], z = th[3 * i + 2];
        float4 v; v.x = x; v.y = y; v.z = z; v.w = x * x + y * y + z * z;
        th4[i] = v;
        srow[i] = 0.0f;
        jminrow[i] = 0xFFFFFFFFu;
        negrow[i] = 0u;
    }
    if (i == 0) { *d2mb = 0u; gacc[0] = 0.0f; gacc[1] = 0.0f; }
}

// K1: row-normalize embeddings -> bf16 e[N][D], PRE-SCALED by sqrt(10*log2(e)).
// Blocks 0..255 additionally compute the global theta-d2max (th4 ready via kpack).
__global__ void knorm(const float* __restrict__ emb, unsigned short* __restrict__ e,
                      const float4* __restrict__ th4, unsigned* __restrict__ d2mb) {
    int w    = threadIdx.x >> 6;
    int row  = blockIdx.x * 4 + w;
    int lane = threadIdx.x & 63;
    const float4* src = (const float4*)(emb + (size_t)row * D);
    float4 v0 = src[lane * 2];
    float4 v1 = src[lane * 2 + 1];
    float ss = v0.x*v0.x + v0.y*v0.y + v0.z*v0.z + v0.w*v0.w
             + v1.x*v1.x + v1.y*v1.y + v1.z*v1.z + v1.w*v1.w;
#pragma unroll
    for (int off = 1; off < 64; off <<= 1) ss += __shfl_xor(ss, off, 64);
    // 3.7982826^2 = 14.42695 = 10*log2(e): acc becomes exp2 argument directly
    float inv = 3.7982826f / fmaxf(sqrtf(ss), 1e-12f);
    unsigned short h0 = f2bf(v0.x * inv), h1 = f2bf(v0.y * inv);
    unsigned short h2 = f2bf(v0.z * inv), h3 = f2bf(v0.w * inv);
    unsigned short h4 = f2bf(v1.x * inv), h5 = f2bf(v1.y * inv);
    unsigned short h6 = f2bf(v1.z * inv), h7 = f2bf(v1.w * inv);
    uint4 pk;
    pk.x = (unsigned)h0 | ((unsigned)h1 << 16);
    pk.y = (unsigned)h2 | ((unsigned)h3 << 16);
    pk.z = (unsigned)h4 | ((unsigned)h5 << 16);
    pk.w = (unsigned)h6 | ((unsigned)h7 << 16);
    ((uint4*)(e + (size_t)row * D))[lane] = pk;

    if (blockIdx.x < 256) {
        int widx = blockIdx.x * 4 + w;
        int q0 = widx * 4;
        int m0 = N - 4 - q0;
        float4 a0 = th4[q0], a1 = th4[q0 + 1], a2 = th4[q0 + 2], a3 = th4[q0 + 3];
        float4 b0 = th4[m0], b1 = th4[m0 + 1], b2 = th4[m0 + 2], b3 = th4[m0 + 3];
        float m = 0.0f;
        for (int j = q0 + 1 + lane; j < N; j += 64) {
            float4 tj = th4[j];
            float d;
            d = a0.w + tj.w - 2.0f * (a0.x*tj.x + a0.y*tj.y + a0.z*tj.z); m = fmaxf(m, d);
            d = a1.w + tj.w - 2.0f * (a1.x*tj.x + a1.y*tj.y + a1.z*tj.z); m = fmaxf(m, d);
            d = a2.w + tj.w - 2.0f * (a2.x*tj.x + a2.y*tj.y + a2.z*tj.z); m = fmaxf(m, d);
            d = a3.w + tj.w - 2.0f * (a3.x*tj.x + a3.y*tj.y + a3.z*tj.z); m = fmaxf(m, d);
        }
        for (int j = m0 + 1 + lane; j < N; j += 64) {
            float4 tj = th4[j];
            float d;
            d = b0.w + tj.w - 2.0f * (b0.x*tj.x + b0.y*tj.y + b0.z*tj.z); m = fmaxf(m, d);
            d = b1.w + tj.w - 2.0f * (b1.x*tj.x + b1.y*tj.y + b1.z*tj.z); m = fmaxf(m, d);
            d = b2.w + tj.w - 2.0f * (b2.x*tj.x + b2.y*tj.y + b2.z*tj.z); m = fmaxf(m, d);
            d = b3.w + tj.w - 2.0f * (b3.x*tj.x + b3.y*tj.y + b3.z*tj.z); m = fmaxf(m, d);
        }
#pragma unroll
        for (int off = 1; off < 64; off <<= 1) m = fmaxf(m, __shfl_xor(m, off, 64));
        if (lane == 0) atomicMax(d2mb, __float_as_uint(m));
    }
}

// K4: symmetric fused GEMM, 128x128 tile over the 64x64 triangle grid (2080 blocks),
// 256 threads = 4 waves (2Mx2N, 64x64/wave, acc 4x4). BK=32, double-buffered 32 KB
// LDS -> multiple co-resident blocks/CU (r12-proven best: 80.7 us, VGPR 84).
// BYTE-IDENTICAL to round 12's kmain.
__global__ __launch_bounds__(256) void kmain(
    const unsigned short* __restrict__ e, const float4* __restrict__ th4,
    const unsigned* __restrict__ d2mb, float* __restrict__ srow,
    unsigned* __restrict__ jminrow, unsigned* __restrict__ negrow) {
    __shared__ __align__(16) char smem[32768];   // 2 bufs x (A 8K + B 8K)

    const int tid  = threadIdx.x;
    const int lane = tid & 63;
    const int w    = tid >> 6;        // 0..3
    const int wr   = w >> 1;          // 0..1 (M 64-half)
    const int wc   = w & 1;           // 0..1 (N 64-half)

    // XCD-aware bijective swizzle: 2080 = 8 XCDs x 260; triangle decode (64 rows)
    const int bid = (int)blockIdx.x;
    const int swz = (bid & 7) * 260 + (bid >> 3);
    int rb = (int)((129.0f - sqrtf(16641.0f - 8.0f * (float)swz)) * 0.5f);
    rb = rb < 0 ? 0 : (rb > 63 ? 63 : rb);
    while (tri_cum(rb + 1) <= swz) rb++;
    while (tri_cum(rb) > swz) rb--;
    const int cb = rb + (swz - tri_cum(rb));
    const bool isdiag = (rb == cb);
    const int r0 = rb * 128, c0 = cb * 128;

    // staging (BK=32): per buf, A = 128 rows x 64 B at [0], B at [8192].
    // thread t pass p: row = (t>>2) + 64p, slot = t&3; LDS dest linear t*16
    // (+4096/pass). global slot pre-swizzled: LDS[row][s] = g(row, s^((row>>1)&3)).
    const int ssw = (((tid & 3) ^ ((tid >> 3) & 3)) << 3);   // element offset
    const unsigned short* pA0 = e + (size_t)(r0 + (tid >> 2)) * D + ssw;
    const unsigned short* pA1 = pA0 + (size_t)64 * D;
    const unsigned short* pB0 = e + (size_t)(c0 + (tid >> 2)) * D + ssw;
    const unsigned short* pB1 = pB0 + (size_t)64 * D;

    const int fr = lane & 15;
    const int fq = lane >> 4;
    const int kslot = (fq ^ ((fr >> 1) & 3)) << 4;   // swizzled 16B slot (const/lane)

    f32x4 acc[4][4];
#pragma unroll
    for (int mt = 0; mt < 4; mt++)
#pragma unroll
        for (int nt = 0; nt < 4; nt++) acc[mt][nt] = (f32x4){0.f, 0.f, 0.f, 0.f};

#define STAGE(T, BUF) { \
    const int k0_ = (T) * 32; char* d_ = smem + (BUF) * 16384;   \
    gl_lds16(pA0 + k0_, d_ + tid * 16);                          \
    gl_lds16(pA1 + k0_, d_ + 4096 + tid * 16);                   \
    gl_lds16(pB0 + k0_, d_ + 8192 + tid * 16);                   \
    gl_lds16(pB1 + k0_, d_ + 12288 + tid * 16); }

#define COMPUTE(BUF) { \
    const char* cA_ = smem + (BUF) * 16384;                      \
    const char* cB_ = cA_ + 8192;                                \
    short8 a_[4], b_[4];                                         \
    _Pragma("unroll")                                            \
    for (int mt = 0; mt < 4; mt++)                               \
        a_[mt] = *(const short8*)(cA_ + (wr * 64 + mt * 16 + fr) * 64 + kslot); \
    _Pragma("unroll")                                            \
    for (int nt = 0; nt < 4; nt++)                               \
        b_[nt] = *(const short8*)(cB_ + (wc * 64 + nt * 16 + fr) * 64 + kslot); \
    _Pragma("unroll")                                            \
    for (int mt = 0; mt < 4; mt++)                               \
    _Pragma("unroll")                                            \
    for (int nt = 0; nt < 4; nt++)                               \
        acc[mt][nt] = __builtin_amdgcn_mfma_f32_16x16x32_bf16(   \
            a_[mt], b_[nt], acc[mt][nt], 0, 0, 0); }

#define KST(T)                                                    \
    if ((T) + 1 < 16) STAGE((T) + 1, ((T) + 1) & 1)               \
    COMPUTE((T) & 1)                                              \
    asm volatile("s_waitcnt vmcnt(0)" ::: "memory");              \
    __builtin_amdgcn_s_barrier();                                 \
    __builtin_amdgcn_sched_barrier(0);

    STAGE(0, 0)
    asm volatile("s_waitcnt vmcnt(0)" ::: "memory");
    __builtin_amdgcn_s_barrier();
    __builtin_amdgcn_sched_barrier(0);
    KST(0)  KST(1)  KST(2)  KST(3)
    KST(4)  KST(5)  KST(6)  KST(7)
    KST(8)  KST(9)  KST(10) KST(11)
    KST(12) KST(13) KST(14) KST(15)
#undef KST
#undef COMPUTE
#undef STAGE
    __syncthreads();   // LDS reused by the reduction below

    // ---- fused epilogue (acc is the exp2 argument directly) ----
    const float dmax = sqrtf(__uint_as_float(*d2mb)) + 1e-8f;
    const float p2 = 0.0225f * dmax * dmax;   // (0.15*dmax)^2
    const float n2 = 0.1225f * dmax * dmax;   // (0.35*dmax)^2

    const int j0 = c0 + wc * 64 + fr;
    float4 thj[4];
#pragma unroll
    for (int nt = 0; nt < 4; nt++) thj[nt] = th4[j0 + nt * 16];

    float*    lds_rs = (float*)smem;              // [2][128] row sums (by wc)
    unsigned* lds_rj = (unsigned*)(smem + 1024);
    unsigned* lds_rn = (unsigned*)(smem + 2048);
    float*    lds_cs = (float*)(smem + 3072);     // [2][128] col sums (by wr)
    unsigned* lds_cj = (unsigned*)(smem + 4096);
    unsigned* lds_cn = (unsigned*)(smem + 5120);

    float    csum[4]; unsigned cjm[4], cng[4];
#pragma unroll
    for (int nt = 0; nt < 4; nt++) { csum[nt] = 0.0f; cjm[nt] = 0xFFFFFFFFu; cng[nt] = 0u; }

    const int i0 = r0 + wr * 64 + fq * 4;
#pragma unroll
    for (int mt = 0; mt < 4; mt++) {
#pragma unroll
        for (int rr = 0; rr < 4; rr++) {
            const int i = i0 + mt * 16 + rr;
            const float4 ti = th4[i];
            float sv = 0.0f; unsigned jv = 0xFFFFFFFFu, nv = 0u;
#pragma unroll
            for (int nt = 0; nt < 4; nt++) {
                const int j = j0 + nt * 16;
                const float4 tj = thj[nt];
                float dot = ti.x * tj.x + ti.y * tj.y + ti.z * tj.z;
                float d2 = fmaf(-2.0f, dot, ti.w + tj.w);
                bool pos = isdiag ? ((d2 < p2) && (j != i)) : (d2 < p2);
                bool neg = (d2 > n2);
                float c = (pos || neg) ? exp2f(acc[mt][nt][rr]) : 0.0f;
                sv += c;
                if (neg) nv = 1u;
                if (pos) jv = min(jv, (unsigned)j);
                if (!isdiag) {
                    csum[nt] += c;
                    if (neg) cng[nt] = 1u;
                    if (pos) cjm[nt] = min(cjm[nt], (unsigned)i);
                }
            }
            // row-side reduce across the 16 fr-lanes
#pragma unroll
            for (int off = 1; off < 16; off <<= 1) {
                sv += __shfl_xor(sv, off, 64);
                jv = min(jv, (unsigned)__shfl_xor((int)jv, off, 64));
                nv |= (unsigned)__shfl_xor((int)nv, off, 64);
            }
            if (fr == 0) {
                const int rl = wr * 64 + mt * 16 + fq * 4 + rr;
                lds_rs[wc * 128 + rl] = sv;
                lds_rj[wc * 128 + rl] = jv;
                lds_rn[wc * 128 + rl] = nv;
            }
        }
    }

    // column-side reduce across the 4 fq groups (lane^16, lane^32)
    if (!isdiag) {
#pragma unroll
        for (int nt = 0; nt < 4; nt++) {
            float sv = csum[nt]; unsigned jv = cjm[nt], nv = cng[nt];
#pragma unroll
            for (int off = 16; off < 64; off <<= 1) {
                sv += __shfl_xor(sv, off, 64);
                jv = min(jv, (unsigned)__shfl_xor((int)jv, off, 64));
                nv |= (unsigned)__shfl_xor((int)nv, off, 64);
            }
            if (fq == 0) {
                const int cl = wc * 64 + nt * 16 + fr;
                lds_cs[wr * 128 + cl] = sv;
                lds_cj[wr * 128 + cl] = jv;
                lds_cn[wr * 128 + cl] = nv;
            }
        }
    }
    __syncthreads();
    if (tid < 128) {
        float    sv = lds_rs[tid] + lds_rs[128 + tid];
        unsigned jv = min(lds_rj[tid], lds_rj[128 + tid]);
        unsigned nv = lds_rn[tid] | lds_rn[128 + tid];
        atomicAdd(&srow[r0 + tid], sv);
        atomicMin(&jminrow[r0 + tid], jv);
        atomicOr(&negrow[r0 + tid], nv);
        if (!isdiag) {
            float    cv = lds_cs[tid] + lds_cs[128 + tid];
            unsigned cj = min(lds_cj[tid], lds_cj[128 + tid]);
            unsigned cn = lds_cn[tid] | lds_cn[128 + tid];
            atomicAdd(&srow[c0 + tid], cv);
            atomicMin(&jminrow[c0 + tid], cj);
            atomicOr(&negrow[c0 + tid], cn);
        }
    }
}

// K5: per-row finalize + block-level loss accumulation. e is pre-scaled:
// sim = dot_scaled * ln2. Each block (4 rows) reduces its (p, valid) locally
// and atomicAdds ONE (sum, count) pair into gacc -> kfinal becomes trivial.
__global__ void krow(const unsigned short* __restrict__ e, const float* __restrict__ srow,
                     const unsigned* __restrict__ jminrow, const unsigned* __restrict__ negrow,
                     float* __restrict__ gacc) {
    int w    = threadIdx.x >> 6;
    int row  = blockIdx.x * 4 + w;
    int lane = threadIdx.x & 63;
    unsigned jmv = jminrow[row];
    bool valid = (jmv != 0xFFFFFFFFu) && (negrow[row] != 0u);
    float p = 0.0f;
    if (valid) {
        const uint4* a = (const uint4*)(e + (size_t)row * D);
        const uint4* b = (const uint4*)(e + (size_t)jmv * D);
        uint4 va = a[lane], vb = b[lane];
        float dot = 0.0f;
        dot += bf2f(va.x & 0xFFFFu) * bf2f(vb.x & 0xFFFFu);
        dot += bf2f(va.x >> 16)     * bf2f(vb.x >> 16);
        dot += bf2f(va.y & 0xFFFFu) * bf2f(vb.y & 0xFFFFu);
        dot += bf2f(va.y >> 16)     * bf2f(vb.y >> 16);
        dot += bf2f(va.z & 0xFFFFu) * bf2f(vb.z & 0xFFFFu);
        dot += bf2f(va.z >> 16)     * bf2f(vb.z >> 16);
        dot += bf2f(va.w & 0xFFFFu) * bf2f(vb.w & 0xFFFFu);
        dot += bf2f(va.w >> 16)     * bf2f(vb.w >> 16);
#pragma unroll
        for (int off = 1; off < 64; off <<= 1) dot += __shfl_xor(dot, off, 64);
        p = logf(srow[row]) - dot * 0.69314718f;
    }
    __shared__ float ps[4];
    __shared__ float vs[4];
    if (lane == 0) { ps[w] = p; vs[w] = valid ? 1.0f : 0.0f; }
    __syncthreads();
    if (threadIdx.x == 0) {
        atomicAdd(&gacc[0], ps[0] + ps[1] + ps[2] + ps[3]);
        atomicAdd(&gacc[1], vs[0] + vs[1] + vs[2] + vs[3]);
    }
}

// K6: trivial finalize from the two accumulated scalars.
__global__ void kfinal(const float* __restrict__ gacc, float* __restrict__ out) {
    if (threadIdx.x == 0)
        out[0] = (gacc[1] > 0.0f) ? (gacc[0] / gacc[1]) : 0.0f;
}

extern "C" void kernel_launch(void* const* d_in, const int* in_sizes, int n_in,
                              void* d_out, int out_size, void* d_ws, size_t ws_size,
                              hipStream_t stream) {
    const float* emb = (const float*)d_in[0];
    const float* th  = (const float*)d_in[1];
    float* out = (float*)d_out;
    char* ws = (char*)d_ws;

    unsigned short* e    = (unsigned short*)(ws);
    float4*   th4        = (float4*)(ws + 8388608);
    float*    srow       = (float*)(ws + 8519680);
    unsigned* jminr      = (unsigned*)(ws + 8552448);
    unsigned* negr       = (unsigned*)(ws + 8585216);
    unsigned* d2mb       = (unsigned*)(ws + 8683520);
    float*    gacc       = (float*)(ws + 8683584);

    kpack<<<32, 256, 0, stream>>>(th, th4, srow, jminr, negr, d2mb, gacc);
    knorm<<<N / 4, 256, 0, stream>>>(emb, e, th4, d2mb);
    kmain<<<2080, 256, 0, stream>>>(e, th4, d2mb, srow, jminr, negr);
    krow<<<N / 4, 256, 0, stream>>>(e, srow, jminr, negr, gacc);
    kfinal<<<1, 64, 0, stream>>>(gacc, out);
}

// Round 16
// 127.358 us; speedup vs baseline: 1.3925x; 1.3925x over previous
//
#include <hip/hip_runtime.h>

#define N 8192
#define D 512

typedef __attribute__((ext_vector_type(8))) short short8;
typedef __attribute__((ext_vector_type(4))) float f32x4;

typedef const __attribute__((address_space(1))) unsigned int* gas_t;
typedef __attribute__((address_space(3))) unsigned int* las_t;

static __device__ __forceinline__ unsigned short f2bf(float f) {
    unsigned u = __float_as_uint(f);
    unsigned r = (u + 0x7FFFu + ((u >> 16) & 1u)) >> 16;
    return (unsigned short)r;
}
static __device__ __forceinline__ float bf2f(unsigned u) {
    return __uint_as_float(u << 16);
}
static __device__ __forceinline__ void gl_lds16(const unsigned short* g, char* l) {
    __builtin_amdgcn_global_load_lds((gas_t)g, (las_t)l, 16, 0, 0);
}
// triangle cumulative for the 64x64 grid of 128-wide tiles: row r owns (64-r) tiles
static __device__ __forceinline__ int tri_cum(int r) { return r * (129 - r) / 2; }

// K0: pack thetas -> float4 (x,y,z,|t|^2); init per-row accumulators + d2max.
__global__ void kpack(const float* __restrict__ th, float4* __restrict__ th4,
                      float* __restrict__ srow, unsigned* __restrict__ jminrow,
                      unsigned* __restrict__ negrow, unsigned* __restrict__ d2mb) {
    int i = blockIdx.x * 256 + threadIdx.x;
    if (i < N) {
        float x = th[3 * i], y = th[3 * i + 1], z = th[3 * i + 2];
        float4 v; v.x = x; v.y = y; v.z = z; v.w = x * x + y * y + z * z;
        th4[i] = v;
        srow[i] = 0.0f;
        jminrow[i] = 0xFFFFFFFFu;
        negrow[i] = 0u;
    }
    if (i == 0) *d2mb = 0u;
}

// K1: row-normalize embeddings -> bf16 e[N][D], PRE-SCALED by sqrt(10*log2(e)).
// Blocks 0..255 additionally compute the global theta-d2max (th4 ready via kpack).
__global__ void knorm(const float* __restrict__ emb, unsigned short* __restrict__ e,
                      const float4* __restrict__ th4, unsigned* __restrict__ d2mb) {
    int w    = threadIdx.x >> 6;
    int row  = blockIdx.x * 4 + w;
    int lane = threadIdx.x & 63;
    const float4* src = (const float4*)(emb + (size_t)row * D);
    float4 v0 = src[lane * 2];
    float4 v1 = src[lane * 2 + 1];
    float ss = v0.x*v0.x + v0.y*v0.y + v0.z*v0.z + v0.w*v0.w
             + v1.x*v1.x + v1.y*v1.y + v1.z*v1.z + v1.w*v1.w;
#pragma unroll
    for (int off = 1; off < 64; off <<= 1) ss += __shfl_xor(ss, off, 64);
    // 3.7982826^2 = 14.42695 = 10*log2(e): acc becomes exp2 argument directly
    float inv = 3.7982826f / fmaxf(sqrtf(ss), 1e-12f);
    unsigned short h0 = f2bf(v0.x * inv), h1 = f2bf(v0.y * inv);
    unsigned short h2 = f2bf(v0.z * inv), h3 = f2bf(v0.w * inv);
    unsigned short h4 = f2bf(v1.x * inv), h5 = f2bf(v1.y * inv);
    unsigned short h6 = f2bf(v1.z * inv), h7 = f2bf(v1.w * inv);
    uint4 pk;
    pk.x = (unsigned)h0 | ((unsigned)h1 << 16);
    pk.y = (unsigned)h2 | ((unsigned)h3 << 16);
    pk.z = (unsigned)h4 | ((unsigned)h5 << 16);
    pk.w = (unsigned)h6 | ((unsigned)h7 << 16);
    ((uint4*)(e + (size_t)row * D))[lane] = pk;

    if (blockIdx.x < 256) {
        int widx = blockIdx.x * 4 + w;
        int q0 = widx * 4;
        int m0 = N - 4 - q0;
        float4 a0 = th4[q0], a1 = th4[q0 + 1], a2 = th4[q0 + 2], a3 = th4[q0 + 3];
        float4 b0 = th4[m0], b1 = th4[m0 + 1], b2 = th4[m0 + 2], b3 = th4[m0 + 3];
        float m = 0.0f;
        for (int j = q0 + 1 + lane; j < N; j += 64) {
            float4 tj = th4[j];
            float d;
            d = a0.w + tj.w - 2.0f * (a0.x*tj.x + a0.y*tj.y + a0.z*tj.z); m = fmaxf(m, d);
            d = a1.w + tj.w - 2.0f * (a1.x*tj.x + a1.y*tj.y + a1.z*tj.z); m = fmaxf(m, d);
            d = a2.w + tj.w - 2.0f * (a2.x*tj.x + a2.y*tj.y + a2.z*tj.z); m = fmaxf(m, d);
            d = a3.w + tj.w - 2.0f * (a3.x*tj.x + a3.y*tj.y + a3.z*tj.z); m = fmaxf(m, d);
        }
        for (int j = m0 + 1 + lane; j < N; j += 64) {
            float4 tj = th4[j];
            float d;
            d = b0.w + tj.w - 2.0f * (b0.x*tj.x + b0.y*tj.y + b0.z*tj.z); m = fmaxf(m, d);
            d = b1.w + tj.w - 2.0f * (b1.x*tj.x + b1.y*tj.y + b1.z*tj.z); m = fmaxf(m, d);
            d = b2.w + tj.w - 2.0f * (b2.x*tj.x + b2.y*tj.y + b2.z*tj.z); m = fmaxf(m, d);
            d = b3.w + tj.w - 2.0f * (b3.x*tj.x + b3.y*tj.y + b3.z*tj.z); m = fmaxf(m, d);
        }
#pragma unroll
        for (int off = 1; off < 64; off <<= 1) m = fmaxf(m, __shfl_xor(m, off, 64));
        if (lane == 0) atomicMax(d2mb, __float_as_uint(m));
    }
}

// K4: symmetric fused GEMM, 128x128 tile over the 64x64 triangle grid (2080 blocks),
// 256 threads = 4 waves (2Mx2N, 64x64/wave, acc 4x4). BK=32, double-buffered 32 KB
// LDS -> 4-5 co-resident blocks/CU (the m97/m114 regime; r12-proven best).
// BYTE-IDENTICAL to round 12's kmain.
__global__ __launch_bounds__(256) void kmain(
    const unsigned short* __restrict__ e, const float4* __restrict__ th4,
    const unsigned* __restrict__ d2mb, float* __restrict__ srow,
    unsigned* __restrict__ jminrow, unsigned* __restrict__ negrow) {
    __shared__ __align__(16) char smem[32768];   // 2 bufs x (A 8K + B 8K)

    const int tid  = threadIdx.x;
    const int lane = tid & 63;
    const int w    = tid >> 6;        // 0..3
    const int wr   = w >> 1;          // 0..1 (M 64-half)
    const int wc   = w & 1;           // 0..1 (N 64-half)

    // XCD-aware bijective swizzle: 2080 = 8 XCDs x 260; triangle decode (64 rows)
    const int bid = (int)blockIdx.x;
    const int swz = (bid & 7) * 260 + (bid >> 3);
    int rb = (int)((129.0f - sqrtf(16641.0f - 8.0f * (float)swz)) * 0.5f);
    rb = rb < 0 ? 0 : (rb > 63 ? 63 : rb);
    while (tri_cum(rb + 1) <= swz) rb++;
    while (tri_cum(rb) > swz) rb--;
    const int cb = rb + (swz - tri_cum(rb));
    const bool isdiag = (rb == cb);
    const int r0 = rb * 128, c0 = cb * 128;

    // staging (BK=32): per buf, A = 128 rows x 64 B at [0], B at [8192].
    // thread t pass p: row = (t>>2) + 64p, slot = t&3; LDS dest linear t*16
    // (+4096/pass). global slot pre-swizzled: LDS[row][s] = g(row, s^((row>>1)&3)).
    const int ssw = (((tid & 3) ^ ((tid >> 3) & 3)) << 3);   // element offset
    const unsigned short* pA0 = e + (size_t)(r0 + (tid >> 2)) * D + ssw;
    const unsigned short* pA1 = pA0 + (size_t)64 * D;
    const unsigned short* pB0 = e + (size_t)(c0 + (tid >> 2)) * D + ssw;
    const unsigned short* pB1 = pB0 + (size_t)64 * D;

    const int fr = lane & 15;
    const int fq = lane >> 4;
    const int kslot = (fq ^ ((fr >> 1) & 3)) << 4;   // swizzled 16B slot (const/lane)

    f32x4 acc[4][4];
#pragma unroll
    for (int mt = 0; mt < 4; mt++)
#pragma unroll
        for (int nt = 0; nt < 4; nt++) acc[mt][nt] = (f32x4){0.f, 0.f, 0.f, 0.f};

#define STAGE(T, BUF) { \
    const int k0_ = (T) * 32; char* d_ = smem + (BUF) * 16384;   \
    gl_lds16(pA0 + k0_, d_ + tid * 16);                          \
    gl_lds16(pA1 + k0_, d_ + 4096 + tid * 16);                   \
    gl_lds16(pB0 + k0_, d_ + 8192 + tid * 16);                   \
    gl_lds16(pB1 + k0_, d_ + 12288 + tid * 16); }

#define COMPUTE(BUF) { \
    const char* cA_ = smem + (BUF) * 16384;                      \
    const char* cB_ = cA_ + 8192;                                \
    short8 a_[4], b_[4];                                         \
    _Pragma("unroll")                                            \
    for (int mt = 0; mt < 4; mt++)                               \
        a_[mt] = *(const short8*)(cA_ + (wr * 64 + mt * 16 + fr) * 64 + kslot); \
    _Pragma("unroll")                                            \
    for (int nt = 0; nt < 4; nt++)                               \
        b_[nt] = *(const short8*)(cB_ + (wc * 64 + nt * 16 + fr) * 64 + kslot); \
    _Pragma("unroll")                                            \
    for (int mt = 0; mt < 4; mt++)                               \
    _Pragma("unroll")                                            \
    for (int nt = 0; nt < 4; nt++)                               \
        acc[mt][nt] = __builtin_amdgcn_mfma_f32_16x16x32_bf16(   \
            a_[mt], b_[nt], acc[mt][nt], 0, 0, 0); }

#define KST(T)                                                    \
    if ((T) + 1 < 16) STAGE((T) + 1, ((T) + 1) & 1)               \
    COMPUTE((T) & 1)                                              \
    asm volatile("s_waitcnt vmcnt(0)" ::: "memory");              \
    __builtin_amdgcn_s_barrier();                                 \
    __builtin_amdgcn_sched_barrier(0);

    STAGE(0, 0)
    asm volatile("s_waitcnt vmcnt(0)" ::: "memory");
    __builtin_amdgcn_s_barrier();
    __builtin_amdgcn_sched_barrier(0);
    KST(0)  KST(1)  KST(2)  KST(3)
    KST(4)  KST(5)  KST(6)  KST(7)
    KST(8)  KST(9)  KST(10) KST(11)
    KST(12) KST(13) KST(14) KST(15)
#undef KST
#undef COMPUTE
#undef STAGE
    __syncthreads();   // LDS reused by the reduction below

    // ---- fused epilogue (acc is the exp2 argument directly) ----
    const float dmax = sqrtf(__uint_as_float(*d2mb)) + 1e-8f;
    const float p2 = 0.0225f * dmax * dmax;   // (0.15*dmax)^2
    const float n2 = 0.1225f * dmax * dmax;   // (0.35*dmax)^2

    const int j0 = c0 + wc * 64 + fr;
    float4 thj[4];
#pragma unroll
    for (int nt = 0; nt < 4; nt++) thj[nt] = th4[j0 + nt * 16];

    float*    lds_rs = (float*)smem;              // [2][128] row sums (by wc)
    unsigned* lds_rj = (unsigned*)(smem + 1024);
    unsigned* lds_rn = (unsigned*)(smem + 2048);
    float*    lds_cs = (float*)(smem + 3072);     // [2][128] col sums (by wr)
    unsigned* lds_cj = (unsigned*)(smem + 4096);
    unsigned* lds_cn = (unsigned*)(smem + 5120);

    float    csum[4]; unsigned cjm[4], cng[4];
#pragma unroll
    for (int nt = 0; nt < 4; nt++) { csum[nt] = 0.0f; cjm[nt] = 0xFFFFFFFFu; cng[nt] = 0u; }

    const int i0 = r0 + wr * 64 + fq * 4;
#pragma unroll
    for (int mt = 0; mt < 4; mt++) {
#pragma unroll
        for (int rr = 0; rr < 4; rr++) {
            const int i = i0 + mt * 16 + rr;
            const float4 ti = th4[i];
            float sv = 0.0f; unsigned jv = 0xFFFFFFFFu, nv = 0u;
#pragma unroll
            for (int nt = 0; nt < 4; nt++) {
                const int j = j0 + nt * 16;
                const float4 tj = thj[nt];
                float dot = ti.x * tj.x + ti.y * tj.y + ti.z * tj.z;
                float d2 = fmaf(-2.0f, dot, ti.w + tj.w);
                bool pos = isdiag ? ((d2 < p2) && (j != i)) : (d2 < p2);
                bool neg = (d2 > n2);
                float c = (pos || neg) ? exp2f(acc[mt][nt][rr]) : 0.0f;
                sv += c;
                if (neg) nv = 1u;
                if (pos) jv = min(jv, (unsigned)j);
                if (!isdiag) {
                    csum[nt] += c;
                    if (neg) cng[nt] = 1u;
                    if (pos) cjm[nt] = min(cjm[nt], (unsigned)i);
                }
            }
            // row-side reduce across the 16 fr-lanes
#pragma unroll
            for (int off = 1; off < 16; off <<= 1) {
                sv += __shfl_xor(sv, off, 64);
                jv = min(jv, (unsigned)__shfl_xor((int)jv, off, 64));
                nv |= (unsigned)__shfl_xor((int)nv, off, 64);
            }
            if (fr == 0) {
                const int rl = wr * 64 + mt * 16 + fq * 4 + rr;
                lds_rs[wc * 128 + rl] = sv;
                lds_rj[wc * 128 + rl] = jv;
                lds_rn[wc * 128 + rl] = nv;
            }
        }
    }

    // column-side reduce across the 4 fq groups (lane^16, lane^32)
    if (!isdiag) {
#pragma unroll
        for (int nt = 0; nt < 4; nt++) {
            float sv = csum[nt]; unsigned jv = cjm[nt], nv = cng[nt];
#pragma unroll
            for (int off = 16; off < 64; off <<= 1) {
                sv += __shfl_xor(sv, off, 64);
                jv = min(jv, (unsigned)__shfl_xor((int)jv, off, 64));
                nv |= (unsigned)__shfl_xor((int)nv, off, 64);
            }
            if (fq == 0) {
                const int cl = wc * 64 + nt * 16 + fr;
                lds_cs[wr * 128 + cl] = sv;
                lds_cj[wr * 128 + cl] = jv;
                lds_cn[wr * 128 + cl] = nv;
            }
        }
    }
    __syncthreads();
    if (tid < 128) {
        float    sv = lds_rs[tid] + lds_rs[128 + tid];
        unsigned jv = min(lds_rj[tid], lds_rj[128 + tid]);
        unsigned nv = lds_rn[tid] | lds_rn[128 + tid];
        atomicAdd(&srow[r0 + tid], sv);
        atomicMin(&jminrow[r0 + tid], jv);
        atomicOr(&negrow[r0 + tid], nv);
        if (!isdiag) {
            float    cv = lds_cs[tid] + lds_cs[128 + tid];
            unsigned cj = min(lds_cj[tid], lds_cj[128 + tid]);
            unsigned cn = lds_cn[tid] | lds_cn[128 + tid];
            atomicAdd(&srow[c0 + tid], cv);
            atomicMin(&jminrow[c0 + tid], cj);
            atomicOr(&negrow[c0 + tid], cn);
        }
    }
}

// K5: per-row finalize. e is pre-scaled: sim = dot_scaled * ln2.
__global__ void krow(const unsigned short* __restrict__ e, const float* __restrict__ srow,
                     const unsigned* __restrict__ jminrow, const unsigned* __restrict__ negrow,
                     float* __restrict__ pr, float* __restrict__ vf) {
    int row  = blockIdx.x * 4 + (threadIdx.x >> 6);
    int lane = threadIdx.x & 63;
    unsigned jmv = jminrow[row];
    bool valid = (jmv != 0xFFFFFFFFu) && (negrow[row] != 0u);
    float p = 0.0f;
    if (valid) {
        const uint4* a = (const uint4*)(e + (size_t)row * D);
        const uint4* b = (const uint4*)(e + (size_t)jmv * D);
        uint4 va = a[lane], vb = b[lane];
        float dot = 0.0f;
        dot += bf2f(va.x & 0xFFFFu) * bf2f(vb.x & 0xFFFFu);
        dot += bf2f(va.x >> 16)     * bf2f(vb.x >> 16);
        dot += bf2f(va.y & 0xFFFFu) * bf2f(vb.y & 0xFFFFu);
        dot += bf2f(va.y >> 16)     * bf2f(vb.y >> 16);
        dot += bf2f(va.z & 0xFFFFu) * bf2f(vb.z & 0xFFFFu);
        dot += bf2f(va.z >> 16)     * bf2f(vb.z >> 16);
        dot += bf2f(va.w & 0xFFFFu) * bf2f(vb.w & 0xFFFFu);
        dot += bf2f(va.w >> 16)     * bf2f(vb.w >> 16);
#pragma unroll
        for (int off = 1; off < 64; off <<= 1) dot += __shfl_xor(dot, off, 64);
        p = logf(srow[row]) - dot * 0.69314718f;
    }
    if (lane == 0) { pr[row] = p; vf[row] = valid ? 1.0f : 0.0f; }
}

// K6: deterministic fixed-tree reduction -> scalar loss.
__global__ void kfinal(const float* __restrict__ pr, const float* __restrict__ vf,
                       float* __restrict__ out) {
    __shared__ float ls[1024];
    __shared__ float lc[1024];
    int t = threadIdx.x;
    float sv = 0.0f, cv = 0.0f;
#pragma unroll
    for (int k = 0; k < 8; k++) { sv += pr[t * 8 + k]; cv += vf[t * 8 + k]; }
    ls[t] = sv; lc[t] = cv;
    __syncthreads();
    for (int off = 512; off > 0; off >>= 1) {
        if (t < off) { ls[t] += ls[t + off]; lc[t] += lc[t + off]; }
        __syncthreads();
    }
    if (t == 0) out[0] = (lc[0] > 0.0f) ? (ls[0] / lc[0]) : 0.0f;
}

extern "C" void kernel_launch(void* const* d_in, const int* in_sizes, int n_in,
                              void* d_out, int out_size, void* d_ws, size_t ws_size,
                              hipStream_t stream) {
    const float* emb = (const float*)d_in[0];
    const float* th  = (const float*)d_in[1];
    float* out = (float*)d_out;
    char* ws = (char*)d_ws;

    unsigned short* e    = (unsigned short*)(ws);
    float4*   th4        = (float4*)(ws + 8388608);
    float*    srow       = (float*)(ws + 8519680);
    unsigned* jminr      = (unsigned*)(ws + 8552448);
    unsigned* negr       = (unsigned*)(ws + 8585216);
    float*    pr         = (float*)(ws + 8617984);
    float*    vf         = (float*)(ws + 8650752);
    unsigned* d2mb       = (unsigned*)(ws + 8683520);

    kpack<<<32, 256, 0, stream>>>(th, th4, srow, jminr, negr, d2mb);
    knorm<<<N / 4, 256, 0, stream>>>(emb, e, th4, d2mb);
    kmain<<<2080, 256, 0, stream>>>(e, th4, d2mb, srow, jminr, negr);
    krow<<<N / 4, 256, 0, stream>>>(e, srow, jminr, negr, pr, vf);
    kfinal<<<1, 1024, 0, stream>>>(pr, vf, out);
}

// Round 17
// 115.427 us; speedup vs baseline: 1.5364x; 1.1034x over previous
//
#include <hip/hip_runtime.h>

#define N 8192
#define D 512

typedef __attribute__((ext_vector_type(4))) float f32x4;

typedef const __attribute__((address_space(1))) unsigned int* gas_t;
typedef __attribute__((address_space(3))) unsigned int* las_t;

static __device__ __forceinline__ void gl_lds16(const void* g, char* l) {
    __builtin_amdgcn_global_load_lds((gas_t)g, (las_t)l, 16, 0, 0);
}
// triangle cumulative for the 64x64 grid of 128-wide tiles: row r owns (64-r) tiles
static __device__ __forceinline__ int tri_cum(int r) { return r * (129 - r) / 2; }

// OCP e4m3 encode (RNE, saturate 448; our inputs are <=~0.7 so never saturate)
static __device__ __forceinline__ unsigned f2fp8(float f) {
    unsigned u = __float_as_uint(f);
    unsigned sgn = (u >> 24) & 0x80u;
    unsigned a = u & 0x7FFFFFFFu;
    if (a >= 0x3C800000u) {                               // >= 2^-6: normal
        unsigned t = a + 0x7FFFFu + ((a >> 20) & 1u);     // RNE to 3-bit mantissa
        unsigned code = (((t >> 23) - 120u) << 3) | ((t >> 20) & 7u);
        if (code > 0x7Eu) code = 0x7Eu;                   // clamp to 448
        return sgn | code;
    }
    float af = __uint_as_float(a);
    unsigned m = (unsigned)(af * 512.0f + 0.5f);          // subnormal: m * 2^-9
    return sgn | (m > 8u ? 8u : m);                       // m==8 -> min normal
}
// OCP e4m3 decode (exact)
static __device__ __forceinline__ float fp82f(unsigned c) {
    unsigned e = (c >> 3) & 15u, m = c & 7u;
    float v = (e == 0u) ? (float)m * 0.001953125f
                        : __uint_as_float(((e + 120u) << 23) | (m << 20));
    return (c & 0x80u) ? -v : v;
}

// K0: pack thetas -> float4 (x,y,z,|t|^2); init per-row accumulators + d2max.
__global__ void kpack(const float* __restrict__ th, float4* __restrict__ th4,
                      float* __restrict__ srow, unsigned* __restrict__ jminrow,
                      unsigned* __restrict__ negrow, unsigned* __restrict__ d2mb) {
    int i = blockIdx.x * 256 + threadIdx.x;
    if (i < N) {
        float x = th[3 * i], y = th[3 * i + 1], z = th[3 * i + 2];
        float4 v; v.x = x; v.y = y; v.z = z; v.w = x * x + y * y + z * z;
        th4[i] = v;
        srow[i] = 0.0f;
        jminrow[i] = 0xFFFFFFFFu;
        negrow[i] = 0u;
    }
    if (i == 0) *d2mb = 0u;
}

// K1: row-normalize embeddings -> fp8 e4m3 e[N][D], PRE-SCALED by sqrt(10*log2(e))
// so the GEMM accumulator is directly the exp2 argument. Blocks 0..255 also
// compute the global theta-d2max (th4 ready via kpack).
__global__ void knorm(const float* __restrict__ emb, unsigned char* __restrict__ e,
                      const float4* __restrict__ th4, unsigned* __restrict__ d2mb) {
    int w    = threadIdx.x >> 6;
    int row  = blockIdx.x * 4 + w;
    int lane = threadIdx.x & 63;
    const float4* src = (const float4*)(emb + (size_t)row * D);
    float4 v0 = src[lane * 2];
    float4 v1 = src[lane * 2 + 1];
    float ss = v0.x*v0.x + v0.y*v0.y + v0.z*v0.z + v0.w*v0.w
             + v1.x*v1.x + v1.y*v1.y + v1.z*v1.z + v1.w*v1.w;
#pragma unroll
    for (int off = 1; off < 64; off <<= 1) ss += __shfl_xor(ss, off, 64);
    // 3.7982826^2 = 14.42695 = 10*log2(e): acc becomes exp2 argument directly
    float inv = 3.7982826f / fmaxf(sqrtf(ss), 1e-12f);
    unsigned c0 = f2fp8(v0.x * inv), c1 = f2fp8(v0.y * inv);
    unsigned c2 = f2fp8(v0.z * inv), c3 = f2fp8(v0.w * inv);
    unsigned c4 = f2fp8(v1.x * inv), c5 = f2fp8(v1.y * inv);
    unsigned c6 = f2fp8(v1.z * inv), c7 = f2fp8(v1.w * inv);
    uint2 pk;
    pk.x = c0 | (c1 << 8) | (c2 << 16) | (c3 << 24);
    pk.y = c4 | (c5 << 8) | (c6 << 16) | (c7 << 24);
    ((uint2*)(e + (size_t)row * D))[lane] = pk;

    if (blockIdx.x < 256) {
        int widx = blockIdx.x * 4 + w;
        int q0 = widx * 4;
        int m0 = N - 4 - q0;
        float4 a0 = th4[q0], a1 = th4[q0 + 1], a2 = th4[q0 + 2], a3 = th4[q0 + 3];
        float4 b0 = th4[m0], b1 = th4[m0 + 1], b2 = th4[m0 + 2], b3 = th4[m0 + 3];
        float m = 0.0f;
        for (int j = q0 + 1 + lane; j < N; j += 64) {
            float4 tj = th4[j];
            float d;
            d = a0.w + tj.w - 2.0f * (a0.x*tj.x + a0.y*tj.y + a0.z*tj.z); m = fmaxf(m, d);
            d = a1.w + tj.w - 2.0f * (a1.x*tj.x + a1.y*tj.y + a1.z*tj.z); m = fmaxf(m, d);
            d = a2.w + tj.w - 2.0f * (a2.x*tj.x + a2.y*tj.y + a2.z*tj.z); m = fmaxf(m, d);
            d = a3.w + tj.w - 2.0f * (a3.x*tj.x + a3.y*tj.y + a3.z*tj.z); m = fmaxf(m, d);
        }
        for (int j = m0 + 1 + lane; j < N; j += 64) {
            float4 tj = th4[j];
            float d;
            d = b0.w + tj.w - 2.0f * (b0.x*tj.x + b0.y*tj.y + b0.z*tj.z); m = fmaxf(m, d);
            d = b1.w + tj.w - 2.0f * (b1.x*tj.x + b1.y*tj.y + b1.z*tj.z); m = fmaxf(m, d);
            d = b2.w + tj.w - 2.0f * (b2.x*tj.x + b2.y*tj.y + b2.z*tj.z); m = fmaxf(m, d);
            d = b3.w + tj.w - 2.0f * (b3.x*tj.x + b3.y*tj.y + b3.z*tj.z); m = fmaxf(m, d);
        }
#pragma unroll
        for (int off = 1; off < 64; off <<= 1) m = fmaxf(m, __shfl_xor(m, off, 64));
        if (lane == 0) atomicMax(d2mb, __float_as_uint(m));
    }
}

// K4: symmetric fused GEMM, fp8 e4m3, 128x128 tile over the 64x64 triangle grid
// (2080 blocks), 256 threads = 4 waves (2Mx2N, 64x64/wave, acc 4x4). BK=64,
// double-buffered 32 KB LDS (same residency as r12's proven best) — fp8 halves
// all LDS bytes (stage writes + fragment reads) and halves the barrier count
// (8 K-steps). Row geometry/swizzle byte-identical to r12 (64B rows, 4x16B
// granules). Fragments: ds_read b64 (2 VGPR) -> mfma_f32_16x16x32_fp8_fp8.
// Epilogue identical to r12.
__global__ __launch_bounds__(256) void kmain(
    const unsigned char* __restrict__ e, const float4* __restrict__ th4,
    const unsigned* __restrict__ d2mb, float* __restrict__ srow,
    unsigned* __restrict__ jminrow, unsigned* __restrict__ negrow) {
    __shared__ __align__(16) char smem[32768];   // 2 bufs x (A 8K + B 8K)

    const int tid  = threadIdx.x;
    const int lane = tid & 63;
    const int w    = tid >> 6;        // 0..3
    const int wr   = w >> 1;          // 0..1 (M 64-half)
    const int wc   = w & 1;           // 0..1 (N 64-half)

    // XCD-aware bijective swizzle: 2080 = 8 XCDs x 260; triangle decode (64 rows)
    const int bid = (int)blockIdx.x;
    const int swz = (bid & 7) * 260 + (bid >> 3);
    int rb = (int)((129.0f - sqrtf(16641.0f - 8.0f * (float)swz)) * 0.5f);
    rb = rb < 0 ? 0 : (rb > 63 ? 63 : rb);
    while (tri_cum(rb + 1) <= swz) rb++;
    while (tri_cum(rb) > swz) rb--;
    const int cb = rb + (swz - tri_cum(rb));
    const bool isdiag = (rb == cb);
    const int r0 = rb * 128, c0 = cb * 128;

    // staging (BK=64 fp8): per buf, A = 128 rows x 64 B at [0], B at [8192].
    // thread t pass p: row = (t>>2) + 64p, 16B-granule = t&3; LDS dest linear
    // t*16 (+4096/pass). global granule pre-swizzled:
    // LDS[row][g] = global(row, g ^ ((row>>1)&3)).
    const int ssw = (((tid & 3) ^ ((tid >> 3) & 3)) << 4);   // byte offset
    const unsigned char* pA0 = e + (size_t)(r0 + (tid >> 2)) * D + ssw;
    const unsigned char* pA1 = pA0 + (size_t)64 * D;
    const unsigned char* pB0 = e + (size_t)(c0 + (tid >> 2)) * D + ssw;
    const unsigned char* pB1 = pB0 + (size_t)64 * D;

    const int fr = lane & 15;
    const int fq = lane >> 4;
    // fragment byte offset for K-half ks: granule (ks*2 + fq>>1) ^ ((fr>>1)&3),
    // 8B half = fq&1.  kslot1 = kslot0 ^ 32.
    const int kslot0 = ((((fq >> 1) ^ ((fr >> 1) & 3)) << 4) | ((fq & 1) << 3));

    f32x4 acc[4][4];
#pragma unroll
    for (int mt = 0; mt < 4; mt++)
#pragma unroll
        for (int nt = 0; nt < 4; nt++) acc[mt][nt] = (f32x4){0.f, 0.f, 0.f, 0.f};

#define STAGE(T, BUF) { \
    const int k0_ = (T) * 64; char* d_ = smem + (BUF) * 16384;   \
    gl_lds16(pA0 + k0_, d_ + tid * 16);                          \
    gl_lds16(pA1 + k0_, d_ + 4096 + tid * 16);                   \
    gl_lds16(pB0 + k0_, d_ + 8192 + tid * 16);                   \
    gl_lds16(pB1 + k0_, d_ + 12288 + tid * 16); }

#define COMPUTE(BUF) { \
    const char* cA_ = smem + (BUF) * 16384;                      \
    const char* cB_ = cA_ + 8192;                                \
    _Pragma("unroll")                                            \
    for (int ks = 0; ks < 2; ++ks) {                             \
        const int kb = kslot0 ^ (ks << 5);                       \
        long a_[4], b_[4];                                       \
        _Pragma("unroll")                                        \
        for (int mt = 0; mt < 4; mt++)                           \
            a_[mt] = *(const long*)(cA_ + (wr * 64 + mt * 16 + fr) * 64 + kb); \
        _Pragma("unroll")                                        \
        for (int nt = 0; nt < 4; nt++)                           \
            b_[nt] = *(const long*)(cB_ + (wc * 64 + nt * 16 + fr) * 64 + kb); \
        _Pragma("unroll")                                        \
        for (int mt = 0; mt < 4; mt++)                           \
        _Pragma("unroll")                                        \
        for (int nt = 0; nt < 4; nt++)                           \
            acc[mt][nt] = __builtin_amdgcn_mfma_f32_16x16x32_fp8_fp8( \
                a_[mt], b_[nt], acc[mt][nt], 0, 0, 0);           \
    } }

#define KST(T)                                                    \
    if ((T) + 1 < 8) STAGE((T) + 1, ((T) + 1) & 1)                \
    COMPUTE((T) & 1)                                              \
    asm volatile("s_waitcnt vmcnt(0)" ::: "memory");              \
    __builtin_amdgcn_s_barrier();                                 \
    __builtin_amdgcn_sched_barrier(0);

    STAGE(0, 0)
    asm volatile("s_waitcnt vmcnt(0)" ::: "memory");
    __builtin_amdgcn_s_barrier();
    __builtin_amdgcn_sched_barrier(0);
    KST(0)  KST(1)  KST(2)  KST(3)
    KST(4)  KST(5)  KST(6)  KST(7)
#undef KST
#undef COMPUTE
#undef STAGE
    __syncthreads();   // LDS reused by the reduction below

    // ---- fused epilogue (acc is the exp2 argument directly) ----
    const float dmax = sqrtf(__uint_as_float(*d2mb)) + 1e-8f;
    const float p2 = 0.0225f * dmax * dmax;   // (0.15*dmax)^2
    const float n2 = 0.1225f * dmax * dmax;   // (0.35*dmax)^2

    const int j0 = c0 + wc * 64 + fr;
    float4 thj[4];
#pragma unroll
    for (int nt = 0; nt < 4; nt++) thj[nt] = th4[j0 + nt * 16];

    float*    lds_rs = (float*)smem;              // [2][128] row sums (by wc)
    unsigned* lds_rj = (unsigned*)(smem + 1024);
    unsigned* lds_rn = (unsigned*)(smem + 2048);
    float*    lds_cs = (float*)(smem + 3072);     // [2][128] col sums (by wr)
    unsigned* lds_cj = (unsigned*)(smem + 4096);
    unsigned* lds_cn = (unsigned*)(smem + 5120);

    float    csum[4]; unsigned cjm[4], cng[4];
#pragma unroll
    for (int nt = 0; nt < 4; nt++) { csum[nt] = 0.0f; cjm[nt] = 0xFFFFFFFFu; cng[nt] = 0u; }

    const int i0 = r0 + wr * 64 + fq * 4;
#pragma unroll
    for (int mt = 0; mt < 4; mt++) {
#pragma unroll
        for (int rr = 0; rr < 4; rr++) {
            const int i = i0 + mt * 16 + rr;
            const float4 ti = th4[i];
            float sv = 0.0f; unsigned jv = 0xFFFFFFFFu, nv = 0u;
#pragma unroll
            for (int nt = 0; nt < 4; nt++) {
                const int j = j0 + nt * 16;
                const float4 tj = thj[nt];
                float dot = ti.x * tj.x + ti.y * tj.y + ti.z * tj.z;
                float d2 = fmaf(-2.0f, dot, ti.w + tj.w);
                bool pos = isdiag ? ((d2 < p2) && (j != i)) : (d2 < p2);
                bool neg = (d2 > n2);
                float c = (pos || neg) ? exp2f(acc[mt][nt][rr]) : 0.0f;
                sv += c;
                if (neg) nv = 1u;
                if (pos) jv = min(jv, (unsigned)j);
                if (!isdiag) {
                    csum[nt] += c;
                    if (neg) cng[nt] = 1u;
                    if (pos) cjm[nt] = min(cjm[nt], (unsigned)i);
                }
            }
            // row-side reduce across the 16 fr-lanes
#pragma unroll
            for (int off = 1; off < 16; off <<= 1) {
                sv += __shfl_xor(sv, off, 64);
                jv = min(jv, (unsigned)__shfl_xor((int)jv, off, 64));
                nv |= (unsigned)__shfl_xor((int)nv, off, 64);
            }
            if (fr == 0) {
                const int rl = wr * 64 + mt * 16 + fq * 4 + rr;
                lds_rs[wc * 128 + rl] = sv;
                lds_rj[wc * 128 + rl] = jv;
                lds_rn[wc * 128 + rl] = nv;
            }
        }
    }

    // column-side reduce across the 4 fq groups (lane^16, lane^32)
    if (!isdiag) {
#pragma unroll
        for (int nt = 0; nt < 4; nt++) {
            float sv = csum[nt]; unsigned jv = cjm[nt], nv = cng[nt];
#pragma unroll
            for (int off = 16; off < 64; off <<= 1) {
                sv += __shfl_xor(sv, off, 64);
                jv = min(jv, (unsigned)__shfl_xor((int)jv, off, 64));
                nv |= (unsigned)__shfl_xor((int)nv, off, 64);
            }
            if (fq == 0) {
                const int cl = wc * 64 + nt * 16 + fr;
                lds_cs[wr * 128 + cl] = sv;
                lds_cj[wr * 128 + cl] = jv;
                lds_cn[wr * 128 + cl] = nv;
            }
        }
    }
    __syncthreads();
    if (tid < 128) {
        float    sv = lds_rs[tid] + lds_rs[128 + tid];
        unsigned jv = min(lds_rj[tid], lds_rj[128 + tid]);
        unsigned nv = lds_rn[tid] | lds_rn[128 + tid];
        atomicAdd(&srow[r0 + tid], sv);
        atomicMin(&jminrow[r0 + tid], jv);
        atomicOr(&negrow[r0 + tid], nv);
        if (!isdiag) {
            float    cv = lds_cs[tid] + lds_cs[128 + tid];
            unsigned cj = min(lds_cj[tid], lds_cj[128 + tid]);
            unsigned cn = lds_cn[tid] | lds_cn[128 + tid];
            atomicAdd(&srow[c0 + tid], cv);
            atomicMin(&jminrow[c0 + tid], cj);
            atomicOr(&negrow[c0 + tid], cn);
        }
    }
}

// K5: per-row finalize. e is fp8, pre-scaled: sim = dot_scaled * ln2.
__global__ void krow(const unsigned char* __restrict__ e, const float* __restrict__ srow,
                     const unsigned* __restrict__ jminrow, const unsigned* __restrict__ negrow,
                     float* __restrict__ pr, float* __restrict__ vf) {
    int row  = blockIdx.x * 4 + (threadIdx.x >> 6);
    int lane = threadIdx.x & 63;
    unsigned jmv = jminrow[row];
    bool valid = (jmv != 0xFFFFFFFFu) && (negrow[row] != 0u);
    float p = 0.0f;
    if (valid) {
        const uint2* a = (const uint2*)(e + (size_t)row * D);
        const uint2* b = (const uint2*)(e + (size_t)jmv * D);
        uint2 va = a[lane], vb = b[lane];
        float dot = 0.0f;
#pragma unroll
        for (int k = 0; k < 4; k++)
            dot += fp82f((va.x >> (8 * k)) & 0xFFu) * fp82f((vb.x >> (8 * k)) & 0xFFu);
#pragma unroll
        for (int k = 0; k < 4; k++)
            dot += fp82f((va.y >> (8 * k)) & 0xFFu) * fp82f((vb.y >> (8 * k)) & 0xFFu);
#pragma unroll
        for (int off = 1; off < 64; off <<= 1) dot += __shfl_xor(dot, off, 64);
        p = logf(srow[row]) - dot * 0.69314718f;
    }
    if (lane == 0) { pr[row] = p; vf[row] = valid ? 1.0f : 0.0f; }
}

// K6: deterministic fixed-tree reduction -> scalar loss.
__global__ void kfinal(const float* __restrict__ pr, const float* __restrict__ vf,
                       float* __restrict__ out) {
    __shared__ float ls[1024];
    __shared__ float lc[1024];
    int t = threadIdx.x;
    float sv = 0.0f, cv = 0.0f;
#pragma unroll
    for (int k = 0; k < 8; k++) { sv += pr[t * 8 + k]; cv += vf[t * 8 + k]; }
    ls[t] = sv; lc[t] = cv;
    __syncthreads();
    for (int off = 512; off > 0; off >>= 1) {
        if (t < off) { ls[t] += ls[t + off]; lc[t] += lc[t + off]; }
        __syncthreads();
    }
    if (t == 0) out[0] = (lc[0] > 0.0f) ? (ls[0] / lc[0]) : 0.0f;
}

extern "C" void kernel_launch(void* const* d_in, const int* in_sizes, int n_in,
                              void* d_out, int out_size, void* d_ws, size_t ws_size,
                              hipStream_t stream) {
    const float* emb = (const float*)d_in[0];
    const float* th  = (const float*)d_in[1];
    float* out = (float*)d_out;
    char* ws = (char*)d_ws;

    unsigned char* e     = (unsigned char*)(ws);              // 4 MB fp8 [N][D]
    float4*   th4        = (float4*)(ws + 8388608);
    float*    srow       = (float*)(ws + 8519680);
    unsigned* jminr      = (unsigned*)(ws + 8552448);
    unsigned* negr       = (unsigned*)(ws + 8585216);
    float*    pr         = (float*)(ws + 8617984);
    float*    vf         = (float*)(ws + 8650752);
    unsigned* d2mb       = (unsigned*)(ws + 8683520);

    kpack<<<32, 256, 0, stream>>>(th, th4, srow, jminr, negr, d2mb);
    knorm<<<N / 4, 256, 0, stream>>>(emb, e, th4, d2mb);
    kmain<<<2080, 256, 0, stream>>>(e, th4, d2mb, srow, jminr, negr);
    krow<<<N / 4, 256, 0, stream>>>(e, srow, jminr, negr, pr, vf);
    kfinal<<<1, 1024, 0, stream>>>(pr, vf, out);
}

// Round 18
// 112.268 us; speedup vs baseline: 1.5796x; 1.0281x over previous
//
#include <hip/hip_runtime.h>

#define N 8192
#define D 512

typedef __attribute__((ext_vector_type(4))) float f32x4;
typedef __attribute__((ext_vector_type(2))) long long2v;

typedef const __attribute__((address_space(1))) unsigned int* gas_t;
typedef __attribute__((address_space(3))) unsigned int* las_t;

static __device__ __forceinline__ void gl_lds16(const void* g, char* l) {
    __builtin_amdgcn_global_load_lds((gas_t)g, (las_t)l, 16, 0, 0);
}
// triangle cumulative for the 64x64 grid of 128-wide tiles: row r owns (64-r) tiles
static __device__ __forceinline__ int tri_cum(int r) { return r * (129 - r) / 2; }

// OCP e4m3 encode (RNE, saturate 448; our inputs are <=~0.7 so never saturate)
static __device__ __forceinline__ unsigned f2fp8(float f) {
    unsigned u = __float_as_uint(f);
    unsigned sgn = (u >> 24) & 0x80u;
    unsigned a = u & 0x7FFFFFFFu;
    if (a >= 0x3C800000u) {                               // >= 2^-6: normal
        unsigned t = a + 0x7FFFFu + ((a >> 20) & 1u);     // RNE to 3-bit mantissa
        unsigned code = (((t >> 23) - 120u) << 3) | ((t >> 20) & 7u);
        if (code > 0x7Eu) code = 0x7Eu;                   // clamp to 448
        return sgn | code;
    }
    float af = __uint_as_float(a);
    unsigned m = (unsigned)(af * 512.0f + 0.5f);          // subnormal: m * 2^-9
    return sgn | (m > 8u ? 8u : m);                       // m==8 -> min normal
}
// OCP e4m3 decode (exact)
static __device__ __forceinline__ float fp82f(unsigned c) {
    unsigned e = (c >> 3) & 15u, m = c & 7u;
    float v = (e == 0u) ? (float)m * 0.001953125f
                        : __uint_as_float(((e + 120u) << 23) | (m << 20));
    return (c & 0x80u) ? -v : v;
}

// K0: pack thetas -> float4 (x,y,z,|t|^2); init per-row accumulators + d2max.
__global__ void kpack(const float* __restrict__ th, float4* __restrict__ th4,
                      float* __restrict__ srow, unsigned* __restrict__ jminrow,
                      unsigned* __restrict__ negrow, unsigned* __restrict__ d2mb) {
    int i = blockIdx.x * 256 + threadIdx.x;
    if (i < N) {
        float x = th[3 * i], y = th[3 * i + 1], z = th[3 * i + 2];
        float4 v; v.x = x; v.y = y; v.z = z; v.w = x * x + y * y + z * z;
        th4[i] = v;
        srow[i] = 0.0f;
        jminrow[i] = 0xFFFFFFFFu;
        negrow[i] = 0u;
    }
    if (i == 0) *d2mb = 0u;
}

// K1: row-normalize embeddings -> fp8 e4m3 e[N][D], PRE-SCALED by sqrt(10*log2(e)).
// Each 64B K-chunk is stored with its 8B units PERMUTED to [0,4,1,5,2,6,3,7] so a
// single 16B granule G holds units (G, G+4) = both K-half fragments one lane needs
// (kmain reads ds_read_b128, conflict-free; krow's dot is permutation-invariant).
// Blocks 0..255 also compute the global theta-d2max (th4 ready via kpack).
__global__ void knorm(const float* __restrict__ emb, unsigned char* __restrict__ e,
                      const float4* __restrict__ th4, unsigned* __restrict__ d2mb) {
    int w    = threadIdx.x >> 6;
    int row  = blockIdx.x * 4 + w;
    int lane = threadIdx.x & 63;
    const float4* src = (const float4*)(emb + (size_t)row * D);
    float4 v0 = src[lane * 2];
    float4 v1 = src[lane * 2 + 1];
    float ss = v0.x*v0.x + v0.y*v0.y + v0.z*v0.z + v0.w*v0.w
             + v1.x*v1.x + v1.y*v1.y + v1.z*v1.z + v1.w*v1.w;
#pragma unroll
    for (int off = 1; off < 64; off <<= 1) ss += __shfl_xor(ss, off, 64);
    // 3.7982826^2 = 14.42695 = 10*log2(e): acc becomes exp2 argument directly
    float inv = 3.7982826f / fmaxf(sqrtf(ss), 1e-12f);
    unsigned c0 = f2fp8(v0.x * inv), c1 = f2fp8(v0.y * inv);
    unsigned c2 = f2fp8(v0.z * inv), c3 = f2fp8(v0.w * inv);
    unsigned c4 = f2fp8(v1.x * inv), c5 = f2fp8(v1.y * inv);
    unsigned c6 = f2fp8(v1.z * inv), c7 = f2fp8(v1.w * inv);
    uint2 pk;
    pk.x = c0 | (c1 << 8) | (c2 << 16) | (c3 << 24);
    pk.y = c4 | (c5 << 8) | (c6 << 16) | (c7 << 24);
    // permuted store: lane covers K [lane*8, lane*8+8) = chunk c, unit u
    {
        int c = lane >> 3, u = lane & 7;
        int off8 = c * 64 + ((u < 4) ? u * 16 : (u - 4) * 16 + 8);
        *(uint2*)(e + (size_t)row * D + off8) = pk;
    }

    if (blockIdx.x < 256) {
        int widx = blockIdx.x * 4 + w;
        int q0 = widx * 4;
        int m0 = N - 4 - q0;
        float4 a0 = th4[q0], a1 = th4[q0 + 1], a2 = th4[q0 + 2], a3 = th4[q0 + 3];
        float4 b0 = th4[m0], b1 = th4[m0 + 1], b2 = th4[m0 + 2], b3 = th4[m0 + 3];
        float m = 0.0f;
        for (int j = q0 + 1 + lane; j < N; j += 64) {
            float4 tj = th4[j];
            float d;
            d = a0.w + tj.w - 2.0f * (a0.x*tj.x + a0.y*tj.y + a0.z*tj.z); m = fmaxf(m, d);
            d = a1.w + tj.w - 2.0f * (a1.x*tj.x + a1.y*tj.y + a1.z*tj.z); m = fmaxf(m, d);
            d = a2.w + tj.w - 2.0f * (a2.x*tj.x + a2.y*tj.y + a2.z*tj.z); m = fmaxf(m, d);
            d = a3.w + tj.w - 2.0f * (a3.x*tj.x + a3.y*tj.y + a3.z*tj.z); m = fmaxf(m, d);
        }
        for (int j = m0 + 1 + lane; j < N; j += 64) {
            float4 tj = th4[j];
            float d;
            d = b0.w + tj.w - 2.0f * (b0.x*tj.x + b0.y*tj.y + b0.z*tj.z); m = fmaxf(m, d);
            d = b1.w + tj.w - 2.0f * (b1.x*tj.x + b1.y*tj.y + b1.z*tj.z); m = fmaxf(m, d);
            d = b2.w + tj.w - 2.0f * (b2.x*tj.x + b2.y*tj.y + b2.z*tj.z); m = fmaxf(m, d);
            d = b3.w + tj.w - 2.0f * (b3.x*tj.x + b3.y*tj.y + b3.z*tj.z); m = fmaxf(m, d);
        }
#pragma unroll
        for (int off = 1; off < 64; off <<= 1) m = fmaxf(m, __shfl_xor(m, off, 64));
        if (lane == 0) atomicMax(d2mb, __float_as_uint(m));
    }
}

// K4: symmetric fused GEMM, fp8 e4m3, 128x128 tile over the 64x64 triangle grid
// (2080 blocks), 256 threads = 4 waves (2Mx2N, 64x64/wave, acc 4x4). BK=64,
// double-buffered 32 KB LDS. With the unit-permuted global layout, each lane's
// TWO K-half fragments sit in one 16B granule -> single ds_read_b128 per fragment
// at row*64 + (fq^((fr>>1)&3))*16 — address-isomorphic to r12's measured
// 0-conflict pattern. Staging macro identical to r17. Epilogue identical to r12.
__global__ __launch_bounds__(256) void kmain(
    const unsigned char* __restrict__ e, const float4* __restrict__ th4,
    const unsigned* __restrict__ d2mb, float* __restrict__ srow,
    unsigned* __restrict__ jminrow, unsigned* __restrict__ negrow) {
    __shared__ __align__(16) char smem[32768];   // 2 bufs x (A 8K + B 8K)

    const int tid  = threadIdx.x;
    const int lane = tid & 63;
    const int w    = tid >> 6;        // 0..3
    const int wr   = w >> 1;          // 0..1 (M 64-half)
    const int wc   = w & 1;           // 0..1 (N 64-half)

    // XCD-aware bijective swizzle: 2080 = 8 XCDs x 260; triangle decode (64 rows)
    const int bid = (int)blockIdx.x;
    const int swz = (bid & 7) * 260 + (bid >> 3);
    int rb = (int)((129.0f - sqrtf(16641.0f - 8.0f * (float)swz)) * 0.5f);
    rb = rb < 0 ? 0 : (rb > 63 ? 63 : rb);
    while (tri_cum(rb + 1) <= swz) rb++;
    while (tri_cum(rb) > swz) rb--;
    const int cb = rb + (swz - tri_cum(rb));
    const bool isdiag = (rb == cb);
    const int r0 = rb * 128, c0 = cb * 128;

    // staging (BK=64 fp8): per buf, A = 128 rows x 64 B at [0], B at [8192].
    // thread t pass p: row = (t>>2) + 64p, 16B-granule = t&3; LDS dest linear
    // t*16 (+4096/pass). global granule pre-swizzled:
    // LDS[row][g] = global(row, g ^ ((row>>1)&3)).
    const int ssw = (((tid & 3) ^ ((tid >> 3) & 3)) << 4);   // byte offset
    const unsigned char* pA0 = e + (size_t)(r0 + (tid >> 2)) * D + ssw;
    const unsigned char* pA1 = pA0 + (size_t)64 * D;
    const unsigned char* pB0 = e + (size_t)(c0 + (tid >> 2)) * D + ssw;
    const unsigned char* pB1 = pB0 + (size_t)64 * D;

    const int fr = lane & 15;
    const int fq = lane >> 4;
    // one b128 per fragment: granule fq ^ ((fr>>1)&3); contains both ks halves
    const int kslot = (fq ^ ((fr >> 1) & 3)) << 4;

    f32x4 acc[4][4];
#pragma unroll
    for (int mt = 0; mt < 4; mt++)
#pragma unroll
        for (int nt = 0; nt < 4; nt++) acc[mt][nt] = (f32x4){0.f, 0.f, 0.f, 0.f};

#define STAGE(T, BUF) { \
    const int k0_ = (T) * 64; char* d_ = smem + (BUF) * 16384;   \
    gl_lds16(pA0 + k0_, d_ + tid * 16);                          \
    gl_lds16(pA1 + k0_, d_ + 4096 + tid * 16);                   \
    gl_lds16(pB0 + k0_, d_ + 8192 + tid * 16);                   \
    gl_lds16(pB1 + k0_, d_ + 12288 + tid * 16); }

#define COMPUTE(BUF) { \
    const char* cA_ = smem + (BUF) * 16384;                      \
    const char* cB_ = cA_ + 8192;                                \
    long2v a_[4], b_[4];                                         \
    _Pragma("unroll")                                            \
    for (int mt = 0; mt < 4; mt++)                               \
        a_[mt] = *(const long2v*)(cA_ + (wr * 64 + mt * 16 + fr) * 64 + kslot); \
    _Pragma("unroll")                                            \
    for (int nt = 0; nt < 4; nt++)                               \
        b_[nt] = *(const long2v*)(cB_ + (wc * 64 + nt * 16 + fr) * 64 + kslot); \
    _Pragma("unroll")                                            \
    for (int mt = 0; mt < 4; mt++)                               \
    _Pragma("unroll")                                            \
    for (int nt = 0; nt < 4; nt++) {                             \
        acc[mt][nt] = __builtin_amdgcn_mfma_f32_16x16x32_fp8_fp8( \
            a_[mt][0], b_[nt][0], acc[mt][nt], 0, 0, 0);         \
        acc[mt][nt] = __builtin_amdgcn_mfma_f32_16x16x32_fp8_fp8( \
            a_[mt][1], b_[nt][1], acc[mt][nt], 0, 0, 0);         \
    } }

#define KST(T)                                                    \
    if ((T) + 1 < 8) STAGE((T) + 1, ((T) + 1) & 1)                \
    COMPUTE((T) & 1)                                              \
    asm volatile("s_waitcnt vmcnt(0)" ::: "memory");              \
    __builtin_amdgcn_s_barrier();                                 \
    __builtin_amdgcn_sched_barrier(0);

    STAGE(0, 0)
    asm volatile("s_waitcnt vmcnt(0)" ::: "memory");
    __builtin_amdgcn_s_barrier();
    __builtin_amdgcn_sched_barrier(0);
    KST(0)  KST(1)  KST(2)  KST(3)
    KST(4)  KST(5)  KST(6)  KST(7)
#undef KST
#undef COMPUTE
#undef STAGE
    __syncthreads();   // LDS reused by the reduction below

    // ---- fused epilogue (acc is the exp2 argument directly) ----
    const float dmax = sqrtf(__uint_as_float(*d2mb)) + 1e-8f;
    const float p2 = 0.0225f * dmax * dmax;   // (0.15*dmax)^2
    const float n2 = 0.1225f * dmax * dmax;   // (0.35*dmax)^2

    const int j0 = c0 + wc * 64 + fr;
    float4 thj[4];
#pragma unroll
    for (int nt = 0; nt < 4; nt++) thj[nt] = th4[j0 + nt * 16];

    float*    lds_rs = (float*)smem;              // [2][128] row sums (by wc)
    unsigned* lds_rj = (unsigned*)(smem + 1024);
    unsigned* lds_rn = (unsigned*)(smem + 2048);
    float*    lds_cs = (float*)(smem + 3072);     // [2][128] col sums (by wr)
    unsigned* lds_cj = (unsigned*)(smem + 4096);
    unsigned* lds_cn = (unsigned*)(smem + 5120);

    float    csum[4]; unsigned cjm[4], cng[4];
#pragma unroll
    for (int nt = 0; nt < 4; nt++) { csum[nt] = 0.0f; cjm[nt] = 0xFFFFFFFFu; cng[nt] = 0u; }

    const int i0 = r0 + wr * 64 + fq * 4;
#pragma unroll
    for (int mt = 0; mt < 4; mt++) {
#pragma unroll
        for (int rr = 0; rr < 4; rr++) {
            const int i = i0 + mt * 16 + rr;
            const float4 ti = th4[i];
            float sv = 0.0f; unsigned jv = 0xFFFFFFFFu, nv = 0u;
#pragma unroll
            for (int nt = 0; nt < 4; nt++) {
                const int j = j0 + nt * 16;
                const float4 tj = thj[nt];
                float dot = ti.x * tj.x + ti.y * tj.y + ti.z * tj.z;
                float d2 = fmaf(-2.0f, dot, ti.w + tj.w);
                bool pos = isdiag ? ((d2 < p2) && (j != i)) : (d2 < p2);
                bool neg = (d2 > n2);
                float c = (pos || neg) ? exp2f(acc[mt][nt][rr]) : 0.0f;
                sv += c;
                if (neg) nv = 1u;
                if (pos) jv = min(jv, (unsigned)j);
                if (!isdiag) {
                    csum[nt] += c;
                    if (neg) cng[nt] = 1u;
                    if (pos) cjm[nt] = min(cjm[nt], (unsigned)i);
                }
            }
            // row-side reduce across the 16 fr-lanes
#pragma unroll
            for (int off = 1; off < 16; off <<= 1) {
                sv += __shfl_xor(sv, off, 64);
                jv = min(jv, (unsigned)__shfl_xor((int)jv, off, 64));
                nv |= (unsigned)__shfl_xor((int)nv, off, 64);
            }
            if (fr == 0) {
                const int rl = wr * 64 + mt * 16 + fq * 4 + rr;
                lds_rs[wc * 128 + rl] = sv;
                lds_rj[wc * 128 + rl] = jv;
                lds_rn[wc * 128 + rl] = nv;
            }
        }
    }

    // column-side reduce across the 4 fq groups (lane^16, lane^32)
    if (!isdiag) {
#pragma unroll
        for (int nt = 0; nt < 4; nt++) {
            float sv = csum[nt]; unsigned jv = cjm[nt], nv = cng[nt];
#pragma unroll
            for (int off = 16; off < 64; off <<= 1) {
                sv += __shfl_xor(sv, off, 64);
                jv = min(jv, (unsigned)__shfl_xor((int)jv, off, 64));
                nv |= (unsigned)__shfl_xor((int)nv, off, 64);
            }
            if (fq == 0) {
                const int cl = wc * 64 + nt * 16 + fr;
                lds_cs[wr * 128 + cl] = sv;
                lds_cj[wr * 128 + cl] = jv;
                lds_cn[wr * 128 + cl] = nv;
            }
        }
    }
    __syncthreads();
    if (tid < 128) {
        float    sv = lds_rs[tid] + lds_rs[128 + tid];
        unsigned jv = min(lds_rj[tid], lds_rj[128 + tid]);
        unsigned nv = lds_rn[tid] | lds_rn[128 + tid];
        atomicAdd(&srow[r0 + tid], sv);
        atomicMin(&jminrow[r0 + tid], jv);
        atomicOr(&negrow[r0 + tid], nv);
        if (!isdiag) {
            float    cv = lds_cs[tid] + lds_cs[128 + tid];
            unsigned cj = min(lds_cj[tid], lds_cj[128 + tid]);
            unsigned cn = lds_cn[tid] | lds_cn[128 + tid];
            atomicAdd(&srow[c0 + tid], cv);
            atomicMin(&jminrow[c0 + tid], cj);
            atomicOr(&negrow[c0 + tid], cn);
        }
    }
}

// K5: per-row finalize. e is fp8 (unit-permuted rows; dot is permutation-invariant),
// pre-scaled: sim = dot_scaled * ln2.
__global__ void krow(const unsigned char* __restrict__ e, const float* __restrict__ srow,
                     const unsigned* __restrict__ jminrow, const unsigned* __restrict__ negrow,
                     float* __restrict__ pr, float* __restrict__ vf) {
    int row  = blockIdx.x * 4 + (threadIdx.x >> 6);
    int lane = threadIdx.x & 63;
    unsigned jmv = jminrow[row];
    bool valid = (jmv != 0xFFFFFFFFu) && (negrow[row] != 0u);
    float p = 0.0f;
    if (valid) {
        const uint2* a = (const uint2*)(e + (size_t)row * D);
        const uint2* b = (const uint2*)(e + (size_t)jmv * D);
        uint2 va = a[lane], vb = b[lane];
        float dot = 0.0f;
#pragma unroll
        for (int k = 0; k < 4; k++)
            dot += fp82f((va.x >> (8 * k)) & 0xFFu) * fp82f((vb.x >> (8 * k)) & 0xFFu);
#pragma unroll
        for (int k = 0; k < 4; k++)
            dot += fp82f((va.y >> (8 * k)) & 0xFFu) * fp82f((vb.y >> (8 * k)) & 0xFFu);
#pragma unroll
        for (int off = 1; off < 64; off <<= 1) dot += __shfl_xor(dot, off, 64);
        p = logf(srow[row]) - dot * 0.69314718f;
    }
    if (lane == 0) { pr[row] = p; vf[row] = valid ? 1.0f : 0.0f; }
}

// K6: deterministic fixed-tree reduction -> scalar loss.
__global__ void kfinal(const float* __restrict__ pr, const float* __restrict__ vf,
                       float* __restrict__ out) {
    __shared__ float ls[1024];
    __shared__ float lc[1024];
    int t = threadIdx.x;
    float sv = 0.0f, cv = 0.0f;
#pragma unroll
    for (int k = 0; k < 8; k++) { sv += pr[t * 8 + k]; cv += vf[t * 8 + k]; }
    ls[t] = sv; lc[t] = cv;
    __syncthreads();
    for (int off = 512; off > 0; off >>= 1) {
        if (t < off) { ls[t] += ls[t + off]; lc[t] += lc[t + off]; }
        __syncthreads();
    }
    if (t == 0) out[0] = (lc[0] > 0.0f) ? (ls[0] / lc[0]) : 0.0f;
}

extern "C" void kernel_launch(void* const* d_in, const int* in_sizes, int n_in,
                              void* d_out, int out_size, void* d_ws, size_t ws_size,
                              hipStream_t stream) {
    const float* emb = (const float*)d_in[0];
    const float* th  = (const float*)d_in[1];
    float* out = (float*)d_out;
    char* ws = (char*)d_ws;

    unsigned char* e     = (unsigned char*)(ws);              // 4 MB fp8 [N][D]
    float4*   th4        = (float4*)(ws + 8388608);
    float*    srow       = (float*)(ws + 8519680);
    unsigned* jminr      = (unsigned*)(ws + 8552448);
    unsigned* negr       = (unsigned*)(ws + 8585216);
    float*    pr         = (float*)(ws + 8617984);
    float*    vf         = (float*)(ws + 8650752);
    unsigned* d2mb       = (unsigned*)(ws + 8683520);

    kpack<<<32, 256, 0, stream>>>(th, th4, srow, jminr, negr, d2mb);
    knorm<<<N / 4, 256, 0, stream>>>(emb, e, th4, d2mb);
    kmain<<<2080, 256, 0, stream>>>(e, th4, d2mb, srow, jminr, negr);
    krow<<<N / 4, 256, 0, stream>>>(e, srow, jminr, negr, pr, vf);
    kfinal<<<1, 1024, 0, stream>>>(pr, vf, out);
}

// Round 19
// 110.817 us; speedup vs baseline: 1.6003x; 1.0131x over previous
//
#include <hip/hip_runtime.h>

#define N 8192
#define D 512

typedef __attribute__((ext_vector_type(4))) float f32x4;
typedef __attribute__((ext_vector_type(2))) long long2v;

typedef const __attribute__((address_space(1))) unsigned int* gas_t;
typedef __attribute__((address_space(3))) unsigned int* las_t;

static __device__ __forceinline__ void gl_lds16(const void* g, char* l) {
    __builtin_amdgcn_global_load_lds((gas_t)g, (las_t)l, 16, 0, 0);
}
// triangle cumulative for the 64x64 grid of 128-wide tiles: row r owns (64-r) tiles
static __device__ __forceinline__ int tri_cum(int r) { return r * (129 - r) / 2; }

// OCP e4m3 encode (RNE, saturate 448; our inputs are <=~0.7 so never saturate)
static __device__ __forceinline__ unsigned f2fp8(float f) {
    unsigned u = __float_as_uint(f);
    unsigned sgn = (u >> 24) & 0x80u;
    unsigned a = u & 0x7FFFFFFFu;
    if (a >= 0x3C800000u) {                               // >= 2^-6: normal
        unsigned t = a + 0x7FFFFu + ((a >> 20) & 1u);     // RNE to 3-bit mantissa
        unsigned code = (((t >> 23) - 120u) << 3) | ((t >> 20) & 7u);
        if (code > 0x7Eu) code = 0x7Eu;                   // clamp to 448
        return sgn | code;
    }
    float af = __uint_as_float(a);
    unsigned m = (unsigned)(af * 512.0f + 0.5f);          // subnormal: m * 2^-9
    return sgn | (m > 8u ? 8u : m);                       // m==8 -> min normal
}
// OCP e4m3 decode (exact)
static __device__ __forceinline__ float fp82f(unsigned c) {
    unsigned e = (c >> 3) & 15u, m = c & 7u;
    float v = (e == 0u) ? (float)m * 0.001953125f
                        : __uint_as_float(((e + 120u) << 23) | (m << 20));
    return (c & 0x80u) ? -v : v;
}

// K1 (runs FIRST): row-normalize embeddings -> fp8 e4m3 e[N][D], PRE-SCALED by
// sqrt(10*log2(e)); 64B K-chunks stored with 8B units permuted [0,4,1,5,2,6,3,7]
// (one 16B granule = both K-half fragments -> conflict-free b128 in kmain).
// Also inits srow/jminrow/negrow for its 4 rows and zeroes d2mb.
__global__ void knorm(const float* __restrict__ emb, unsigned char* __restrict__ e,
                      float* __restrict__ srow, unsigned* __restrict__ jminrow,
                      unsigned* __restrict__ negrow, unsigned* __restrict__ d2mb) {
    int w    = threadIdx.x >> 6;
    int row  = blockIdx.x * 4 + w;
    int lane = threadIdx.x & 63;
    const float4* src = (const float4*)(emb + (size_t)row * D);
    float4 v0 = src[lane * 2];
    float4 v1 = src[lane * 2 + 1];
    float ss = v0.x*v0.x + v0.y*v0.y + v0.z*v0.z + v0.w*v0.w
             + v1.x*v1.x + v1.y*v1.y + v1.z*v1.z + v1.w*v1.w;
#pragma unroll
    for (int off = 1; off < 64; off <<= 1) ss += __shfl_xor(ss, off, 64);
    // 3.7982826^2 = 14.42695 = 10*log2(e): acc becomes exp2 argument directly
    float inv = 3.7982826f / fmaxf(sqrtf(ss), 1e-12f);
    unsigned c0 = f2fp8(v0.x * inv), c1 = f2fp8(v0.y * inv);
    unsigned c2 = f2fp8(v0.z * inv), c3 = f2fp8(v0.w * inv);
    unsigned c4 = f2fp8(v1.x * inv), c5 = f2fp8(v1.y * inv);
    unsigned c6 = f2fp8(v1.z * inv), c7 = f2fp8(v1.w * inv);
    uint2 pk;
    pk.x = c0 | (c1 << 8) | (c2 << 16) | (c3 << 24);
    pk.y = c4 | (c5 << 8) | (c6 << 16) | (c7 << 24);
    {   // permuted store: lane covers K [lane*8, lane*8+8) = chunk c, unit u
        int c = lane >> 3, u = lane & 7;
        int off8 = c * 64 + ((u < 4) ? u * 16 : (u - 4) * 16 + 8);
        *(uint2*)(e + (size_t)row * D + off8) = pk;
    }
    if (lane == 0) {
        srow[row] = 0.0f;
        jminrow[row] = 0xFFFFFFFFu;
        negrow[row] = 0u;
    }
    if (blockIdx.x == 0 && threadIdx.x == 0) *d2mb = 0u;
}

// K2: pack thetas -> float4 (x,y,z,|t|^2) AND global theta-d2max from RAW th
// (no dependency on th4; d2mb zeroed by knorm which runs first).
// 256 blocks: blocks 0..31 also pack; all 1024 waves scan (quad + mirror quad).
__global__ void kth(const float* __restrict__ th, float4* __restrict__ th4,
                    unsigned* __restrict__ d2mb) {
    int tid = threadIdx.x, bid = blockIdx.x;
    if (bid < 32) {
        int i = bid * 256 + tid;
        float x = th[3 * i], y = th[3 * i + 1], z = th[3 * i + 2];
        float4 v; v.x = x; v.y = y; v.z = z; v.w = x * x + y * y + z * z;
        th4[i] = v;
    }
    int w = tid >> 6, lane = tid & 63;
    int widx = bid * 4 + w;             // 0..1023
    int q0 = widx * 4;
    int m0 = N - 4 - q0;
    float4 A[4], B[4];
#pragma unroll
    for (int k = 0; k < 4; k++) {
        float x = th[3 * (q0 + k)], y = th[3 * (q0 + k) + 1], z = th[3 * (q0 + k) + 2];
        A[k].x = x; A[k].y = y; A[k].z = z; A[k].w = x * x + y * y + z * z;
        x = th[3 * (m0 + k)]; y = th[3 * (m0 + k) + 1]; z = th[3 * (m0 + k) + 2];
        B[k].x = x; B[k].y = y; B[k].z = z; B[k].w = x * x + y * y + z * z;
    }
    float m = 0.0f;
    for (int j = q0 + 1 + lane; j < N; j += 64) {
        float x = th[3 * j], y = th[3 * j + 1], z = th[3 * j + 2];
        float tw = x * x + y * y + z * z;
        float d;
        d = A[0].w + tw - 2.0f * (A[0].x*x + A[0].y*y + A[0].z*z); m = fmaxf(m, d);
        d = A[1].w + tw - 2.0f * (A[1].x*x + A[1].y*y + A[1].z*z); m = fmaxf(m, d);
        d = A[2].w + tw - 2.0f * (A[2].x*x + A[2].y*y + A[2].z*z); m = fmaxf(m, d);
        d = A[3].w + tw - 2.0f * (A[3].x*x + A[3].y*y + A[3].z*z); m = fmaxf(m, d);
    }
    for (int j = m0 + 1 + lane; j < N; j += 64) {
        float x = th[3 * j], y = th[3 * j + 1], z = th[3 * j + 2];
        float tw = x * x + y * y + z * z;
        float d;
        d = B[0].w + tw - 2.0f * (B[0].x*x + B[0].y*y + B[0].z*z); m = fmaxf(m, d);
        d = B[1].w + tw - 2.0f * (B[1].x*x + B[1].y*y + B[1].z*z); m = fmaxf(m, d);
        d = B[2].w + tw - 2.0f * (B[2].x*x + B[2].y*y + B[2].z*z); m = fmaxf(m, d);
        d = B[3].w + tw - 2.0f * (B[3].x*x + B[3].y*y + B[3].z*z); m = fmaxf(m, d);
    }
#pragma unroll
    for (int off = 1; off < 64; off <<= 1) m = fmaxf(m, __shfl_xor(m, off, 64));
    __shared__ float red[4];
    if (lane == 0) red[w] = m;
    __syncthreads();
    if (tid == 0) {
        m = fmaxf(fmaxf(red[0], red[1]), fmaxf(red[2], red[3]));
        atomicMax(d2mb, __float_as_uint(m));
    }
}

// K4: symmetric fused GEMM, fp8 e4m3, 128x128 tile over the 64x64 triangle grid
// (2080 blocks), 256 threads = 4 waves (2Mx2N, 64x64/wave, acc 4x4). BK=64,
// THREE 16KB tile-buffers (48 KB LDS): stage(T+2) issued right after the T-barrier,
// per-step wait is a COUNTED vmcnt(4) (stage T+1 stays in flight across the
// barrier) — no mid-loop drain to 0. Fragment reads: single conflict-free
// ds_read_b128 per fragment (unit-permuted global layout). Epilogue = r12's.
__global__ __launch_bounds__(256) void kmain(
    const unsigned char* __restrict__ e, const float4* __restrict__ th4,
    const unsigned* __restrict__ d2mb, float* __restrict__ srow,
    unsigned* __restrict__ jminrow, unsigned* __restrict__ negrow) {
    __shared__ __align__(16) char smem[49152];   // 3 bufs x (A 8K + B 8K)

    const int tid  = threadIdx.x;
    const int lane = tid & 63;
    const int w    = tid >> 6;        // 0..3
    const int wr   = w >> 1;          // 0..1 (M 64-half)
    const int wc   = w & 1;           // 0..1 (N 64-half)

    // XCD-aware bijective swizzle: 2080 = 8 XCDs x 260; triangle decode (64 rows)
    const int bid = (int)blockIdx.x;
    const int swz = (bid & 7) * 260 + (bid >> 3);
    int rb = (int)((129.0f - sqrtf(16641.0f - 8.0f * (float)swz)) * 0.5f);
    rb = rb < 0 ? 0 : (rb > 63 ? 63 : rb);
    while (tri_cum(rb + 1) <= swz) rb++;
    while (tri_cum(rb) > swz) rb--;
    const int cb = rb + (swz - tri_cum(rb));
    const bool isdiag = (rb == cb);
    const int r0 = rb * 128, c0 = cb * 128;

    // staging (BK=64 fp8): per buf, A = 128 rows x 64 B at [0], B at [8192].
    // thread t pass p: row = (t>>2) + 64p, 16B-granule = t&3; LDS dest linear
    // t*16 (+4096/pass). global granule pre-swizzled:
    // LDS[row][g] = global(row, g ^ ((row>>1)&3)).
    const int ssw = (((tid & 3) ^ ((tid >> 3) & 3)) << 4);   // byte offset
    const unsigned char* pA0 = e + (size_t)(r0 + (tid >> 2)) * D + ssw;
    const unsigned char* pA1 = pA0 + (size_t)64 * D;
    const unsigned char* pB0 = e + (size_t)(c0 + (tid >> 2)) * D + ssw;
    const unsigned char* pB1 = pB0 + (size_t)64 * D;

    const int fr = lane & 15;
    const int fq = lane >> 4;
    // one b128 per fragment: granule fq ^ ((fr>>1)&3); contains both ks halves
    const int kslot = (fq ^ ((fr >> 1) & 3)) << 4;

    f32x4 acc[4][4];
#pragma unroll
    for (int mt = 0; mt < 4; mt++)
#pragma unroll
        for (int nt = 0; nt < 4; nt++) acc[mt][nt] = (f32x4){0.f, 0.f, 0.f, 0.f};

#define STAGE(T, BUF) { \
    const int k0_ = (T) * 64; char* d_ = smem + (BUF) * 16384;   \
    gl_lds16(pA0 + k0_, d_ + tid * 16);                          \
    gl_lds16(pA1 + k0_, d_ + 4096 + tid * 16);                   \
    gl_lds16(pB0 + k0_, d_ + 8192 + tid * 16);                   \
    gl_lds16(pB1 + k0_, d_ + 12288 + tid * 16); }

#define COMPUTE(BUF) { \
    const char* cA_ = smem + (BUF) * 16384;                      \
    const char* cB_ = cA_ + 8192;                                \
    long2v a_[4], b_[4];                                         \
    _Pragma("unroll")                                            \
    for (int mt = 0; mt < 4; mt++)                               \
        a_[mt] = *(const long2v*)(cA_ + (wr * 64 + mt * 16 + fr) * 64 + kslot); \
    _Pragma("unroll")                                            \
    for (int nt = 0; nt < 4; nt++)                               \
        b_[nt] = *(const long2v*)(cB_ + (wc * 64 + nt * 16 + fr) * 64 + kslot); \
    _Pragma("unroll")                                            \
    for (int mt = 0; mt < 4; mt++)                               \
    _Pragma("unroll")                                            \
    for (int nt = 0; nt < 4; nt++) {                             \
        acc[mt][nt] = __builtin_amdgcn_mfma_f32_16x16x32_fp8_fp8( \
            a_[mt][0], b_[nt][0], acc[mt][nt], 0, 0, 0);         \
        acc[mt][nt] = __builtin_amdgcn_mfma_f32_16x16x32_fp8_fp8( \
            a_[mt][1], b_[nt][1], acc[mt][nt], 0, 0, 0);         \
    } }

// step: counted wait (stage T landed; T+1 in flight) -> barrier -> issue T+2 -> compute T
#define KST(WAITN, SBUF, DOSTAGE, ST, CBUF)                       \
    asm volatile("s_waitcnt vmcnt(" #WAITN ")" ::: "memory");     \
    __builtin_amdgcn_s_barrier();                                 \
    __builtin_amdgcn_sched_barrier(0);                            \
    if (DOSTAGE) STAGE(ST, SBUF)                                  \
    COMPUTE(CBUF)

    STAGE(0, 0)
    STAGE(1, 1)
    KST(4, 2, 1, 2, 0)   // T=0
    KST(4, 0, 1, 3, 1)   // T=1
    KST(4, 1, 1, 4, 2)   // T=2
    KST(4, 2, 1, 5, 0)   // T=3
    KST(4, 0, 1, 6, 1)   // T=4
    KST(4, 1, 1, 7, 2)   // T=5
    KST(4, 0, 0, 0, 0)   // T=6 (no stage)
    KST(0, 0, 0, 0, 1)   // T=7 (final drain)
#undef KST
#undef COMPUTE
#undef STAGE
    __syncthreads();   // all compute done; LDS reused by the reduction below

    // ---- fused epilogue (acc is the exp2 argument directly) ----
    const float dmax = sqrtf(__uint_as_float(*d2mb)) + 1e-8f;
    const float p2 = 0.0225f * dmax * dmax;   // (0.15*dmax)^2
    const float n2 = 0.1225f * dmax * dmax;   // (0.35*dmax)^2

    const int j0 = c0 + wc * 64 + fr;
    float4 thj[4];
#pragma unroll
    for (int nt = 0; nt < 4; nt++) thj[nt] = th4[j0 + nt * 16];

    float*    lds_rs = (float*)smem;              // [2][128] row sums (by wc)
    unsigned* lds_rj = (unsigned*)(smem + 1024);
    unsigned* lds_rn = (unsigned*)(smem + 2048);
    float*    lds_cs = (float*)(smem + 3072);     // [2][128] col sums (by wr)
    unsigned* lds_cj = (unsigned*)(smem + 4096);
    unsigned* lds_cn = (unsigned*)(smem + 5120);

    float    csum[4]; unsigned cjm[4], cng[4];
#pragma unroll
    for (int nt = 0; nt < 4; nt++) { csum[nt] = 0.0f; cjm[nt] = 0xFFFFFFFFu; cng[nt] = 0u; }

    const int i0 = r0 + wr * 64 + fq * 4;
#pragma unroll
    for (int mt = 0; mt < 4; mt++) {
#pragma unroll
        for (int rr = 0; rr < 4; rr++) {
            const int i = i0 + mt * 16 + rr;
            const float4 ti = th4[i];
            float sv = 0.0f; unsigned jv = 0xFFFFFFFFu, nv = 0u;
#pragma unroll
            for (int nt = 0; nt < 4; nt++) {
                const int j = j0 + nt * 16;
                const float4 tj = thj[nt];
                float dot = ti.x * tj.x + ti.y * tj.y + ti.z * tj.z;
                float d2 = fmaf(-2.0f, dot, ti.w + tj.w);
                bool pos = isdiag ? ((d2 < p2) && (j != i)) : (d2 < p2);
                bool neg = (d2 > n2);
                float c = (pos || neg) ? exp2f(acc[mt][nt][rr]) : 0.0f;
                sv += c;
                if (neg) nv = 1u;
                if (pos) jv = min(jv, (unsigned)j);
                if (!isdiag) {
                    csum[nt] += c;
                    if (neg) cng[nt] = 1u;
                    if (pos) cjm[nt] = min(cjm[nt], (unsigned)i);
                }
            }
            // row-side reduce across the 16 fr-lanes
#pragma unroll
            for (int off = 1; off < 16; off <<= 1) {
                sv += __shfl_xor(sv, off, 64);
                jv = min(jv, (unsigned)__shfl_xor((int)jv, off, 64));
                nv |= (unsigned)__shfl_xor((int)nv, off, 64);
            }
            if (fr == 0) {
                const int rl = wr * 64 + mt * 16 + fq * 4 + rr;
                lds_rs[wc * 128 + rl] = sv;
                lds_rj[wc * 128 + rl] = jv;
                lds_rn[wc * 128 + rl] = nv;
            }
        }
    }

    // column-side reduce across the 4 fq groups (lane^16, lane^32)
    if (!isdiag) {
#pragma unroll
        for (int nt = 0; nt < 4; nt++) {
            float sv = csum[nt]; unsigned jv = cjm[nt], nv = cng[nt];
#pragma unroll
            for (int off = 16; off < 64; off <<= 1) {
                sv += __shfl_xor(sv, off, 64);
                jv = min(jv, (unsigned)__shfl_xor((int)jv, off, 64));
                nv |= (unsigned)__shfl_xor((int)nv, off, 64);
            }
            if (fq == 0) {
                const int cl = wc * 64 + nt * 16 + fr;
                lds_cs[wr * 128 + cl] = sv;
                lds_cj[wr * 128 + cl] = jv;
                lds_cn[wr * 128 + cl] = nv;
            }
        }
    }
    __syncthreads();
    if (tid < 128) {
        float    sv = lds_rs[tid] + lds_rs[128 + tid];
        unsigned jv = min(lds_rj[tid], lds_rj[128 + tid]);
        unsigned nv = lds_rn[tid] | lds_rn[128 + tid];
        atomicAdd(&srow[r0 + tid], sv);
        atomicMin(&jminrow[r0 + tid], jv);
        atomicOr(&negrow[r0 + tid], nv);
        if (!isdiag) {
            float    cv = lds_cs[tid] + lds_cs[128 + tid];
            unsigned cj = min(lds_cj[tid], lds_cj[128 + tid]);
            unsigned cn = lds_cn[tid] | lds_cn[128 + tid];
            atomicAdd(&srow[c0 + tid], cv);
            atomicMin(&jminrow[c0 + tid], cj);
            atomicOr(&negrow[c0 + tid], cn);
        }
    }
}

// K5: per-row finalize. e is fp8 (unit-permuted rows; dot is permutation-invariant),
// pre-scaled: sim = dot_scaled * ln2.
__global__ void krow(const unsigned char* __restrict__ e, const float* __restrict__ srow,
                     const unsigned* __restrict__ jminrow, const unsigned* __restrict__ negrow,
                     float* __restrict__ pr, float* __restrict__ vf) {
    int row  = blockIdx.x * 4 + (threadIdx.x >> 6);
    int lane = threadIdx.x & 63;
    unsigned jmv = jminrow[row];
    bool valid = (jmv != 0xFFFFFFFFu) && (negrow[row] != 0u);
    float p = 0.0f;
    if (valid) {
        const uint2* a = (const uint2*)(e + (size_t)row * D);
        const uint2* b = (const uint2*)(e + (size_t)jmv * D);
        uint2 va = a[lane], vb = b[lane];
        float dot = 0.0f;
#pragma unroll
        for (int k = 0; k < 4; k++)
            dot += fp82f((va.x >> (8 * k)) & 0xFFu) * fp82f((vb.x >> (8 * k)) & 0xFFu);
#pragma unroll
        for (int k = 0; k < 4; k++)
            dot += fp82f((va.y >> (8 * k)) & 0xFFu) * fp82f((vb.y >> (8 * k)) & 0xFFu);
#pragma unroll
        for (int off = 1; off < 64; off <<= 1) dot += __shfl_xor(dot, off, 64);
        p = logf(srow[row]) - dot * 0.69314718f;
    }
    if (lane == 0) { pr[row] = p; vf[row] = valid ? 1.0f : 0.0f; }
}

// K6: deterministic fixed-tree reduction -> scalar loss.
__global__ void kfinal(const float* __restrict__ pr, const float* __restrict__ vf,
                       float* __restrict__ out) {
    __shared__ float ls[1024];
    __shared__ float lc[1024];
    int t = threadIdx.x;
    float sv = 0.0f, cv = 0.0f;
#pragma unroll
    for (int k = 0; k < 8; k++) { sv += pr[t * 8 + k]; cv += vf[t * 8 + k]; }
    ls[t] = sv; lc[t] = cv;
    __syncthreads();
    for (int off = 512; off > 0; off >>= 1) {
        if (t < off) { ls[t] += ls[t + off]; lc[t] += lc[t + off]; }
        __syncthreads();
    }
    if (t == 0) out[0] = (lc[0] > 0.0f) ? (ls[0] / lc[0]) : 0.0f;
}

extern "C" void kernel_launch(void* const* d_in, const int* in_sizes, int n_in,
                              void* d_out, int out_size, void* d_ws, size_t ws_size,
                              hipStream_t stream) {
    const float* emb = (const float*)d_in[0];
    const float* th  = (const float*)d_in[1];
    float* out = (float*)d_out;
    char* ws = (char*)d_ws;

    unsigned char* e     = (unsigned char*)(ws);              // 4 MB fp8 [N][D]
    float4*   th4        = (float4*)(ws + 8388608);
    float*    srow       = (float*)(ws + 8519680);
    unsigned* jminr      = (unsigned*)(ws + 8552448);
    unsigned* negr       = (unsigned*)(ws + 8585216);
    float*    pr         = (float*)(ws + 8617984);
    float*    vf         = (float*)(ws + 8650752);
    unsigned* d2mb       = (unsigned*)(ws + 8683520);

    knorm<<<N / 4, 256, 0, stream>>>(emb, e, srow, jminr, negr, d2mb);
    kth<<<256, 256, 0, stream>>>(th, th4, d2mb);
    kmain<<<2080, 256, 0, stream>>>(e, th4, d2mb, srow, jminr, negr);
    krow<<<N / 4, 256, 0, stream>>>(e, srow, jminr, negr, pr, vf);
    kfinal<<<1, 1024, 0, stream>>>(pr, vf, out);
}